// Round 8
// baseline (800.481 us; speedup 1.0000x reference)
//
#include <hip/hip_runtime.h>
#include <cstdint>
#include <cstddef>

typedef __attribute__((ext_vector_type(4))) float f32x4;
typedef __attribute__((ext_vector_type(8))) short short8;

__device__ __forceinline__ float bf2f(unsigned short u) {
  union { unsigned int i; float f; } x; x.i = ((unsigned int)u) << 16; return x.f;
}
__device__ __forceinline__ unsigned short f2bf(float f) {
  union { float f; unsigned int i; } x; x.f = f;
  unsigned int r = x.i + 0x7fffu + ((x.i >> 16) & 1u);
  return (unsigned short)(r >> 16);
}
__device__ __forceinline__ void gload16(unsigned short* lds, const unsigned short* g) {
  __builtin_amdgcn_global_load_lds(
      (const __attribute__((address_space(1))) unsigned int*)g,
      (__attribute__((address_space(3))) unsigned int*)lds, 16, 0, 0);
}

// ---------------------------------------------------------------------------
// prep kernels
// ---------------------------------------------------------------------------
__global__ void k_prepbn(const float* __restrict__ g1, const float* __restrict__ b1,
                         const float* __restrict__ m1, const float* __restrict__ v1,
                         const float* __restrict__ g2, const float* __restrict__ b2,
                         const float* __restrict__ m2, const float* __restrict__ v2,
                         float* __restrict__ s1, float* __restrict__ bb1,
                         float* __restrict__ s2, float* __restrict__ bb2) {
  int i = threadIdx.x;
  if (i < 256) { float s = g1[i] * rsqrtf(v1[i] + 1e-5f); s1[i] = s; bb1[i] = b1[i] - m1[i] * s; }
  if (i < 128) { float s = g2[i] * rsqrtf(v2[i] + 1e-5f); s2[i] = s; bb2[i] = b2[i] - m2[i] * s; }
}

__global__ void k_prepw1(const float* __restrict__ w, unsigned short* __restrict__ wt) {
  int i = blockIdx.x * 256 + threadIdx.x;  // 256*4608
  int o = i / 4608, k = i - o * 4608;
  int cblk = k / 288, r = k - cblk * 288;
  int t = r >> 5, cl = r & 31;
  int ci = cblk * 32 + cl;
  int ty = t / 3, tx = t - ty * 3;
  wt[i] = f2bf(w[((o * 512 + ci) * 3 + ty) * 3 + tx]);
}
__global__ void k_prepw2(const float* __restrict__ w, unsigned short* __restrict__ wt) {
  int i = blockIdx.x * 256 + threadIdx.x;  // 128*2304
  int o = i / 2304, k = i - o * 2304;
  int cblk = k / 288, r = k - cblk * 288;
  int t = r >> 5, cl = r & 31;
  int ci = cblk * 32 + cl;
  int ty = t / 3, tx = t - ty * 3;
  wt[i] = f2bf(w[((o * 256 + ci) * 3 + ty) * 3 + tx]);
}
// w3b[32][128] bf16, rows >=21 zero
__global__ void k_prepw3(const float* __restrict__ w3, unsigned short* __restrict__ w3b) {
  int i = blockIdx.x * 256 + threadIdx.x;  // 4096
  int c = i >> 7, k = i & 127;
  w3b[i] = (c < 21) ? f2bf(w3[c * 128 + k]) : (unsigned short)0;
}

// zero the 1-px halo ring of a padded NHWC tensor
template <int HP, int WP, int C>
__global__ void k_border(unsigned short* __restrict__ p) {
  const int B = 2 * WP + 2 * (HP - 2);
  const int total = 8 * B * (C / 8);
  int i = blockIdx.x * 256 + threadIdx.x;
  if (i >= total) return;
  const int cg = i % (C / 8);
  int b = i / (C / 8);
  const int n = b / B; b -= n * B;
  int y, x;
  if (b < WP) { y = 0; x = b; }
  else if (b < 2 * WP) { y = HP - 1; x = b - WP; }
  else { int r = b - 2 * WP; y = 1 + (r >> 1); x = (r & 1) ? (WP - 1) : 0; }
  short8 z = {0, 0, 0, 0, 0, 0, 0, 0};
  *(short8*)&p[(((long)n * HP + y) * WP + x) * C + cg * 8] = z;
}

// ---------------------------------------------------------------------------
// feat_T[n][px][512] bf16 from feature[n][512][px] fp32 (coalesced reads)
// ---------------------------------------------------------------------------
__global__ __launch_bounds__(256)
void k_featT(const float* __restrict__ feat, unsigned short* __restrict__ featT) {
  const int g = blockIdx.x * 256 + threadIdx.x;  // 73728 px total
  const int n = g / 9216, p = g - n * 9216;
  const int fg0 = blockIdx.y * 16;               // grid.y = 4
  const float* src = feat + (long)n * 512 * 9216 + p;
  unsigned short* dst = featT + ((long)n * 9216 + p) * 512;
  for (int fg = fg0; fg < fg0 + 16; fg++) {
    short8 o;
    #pragma unroll
    for (int j = 0; j < 8; j++) o[j] = (short)f2bf(src[(long)(fg * 8 + j) * 9216]);
    *(short8*)&dst[fg * 8] = o;
  }
}

// ---------------------------------------------------------------------------
// labels / morphology
// ---------------------------------------------------------------------------
__global__ void k_labels(const float* __restrict__ gp, signed char* __restrict__ lab) {
  int p = blockIdx.x * 256 + threadIdx.x;  // 73728
  int n = p / 9216, q = p - n * 9216;
  const float* g = gp + (long)n * 21 * 9216 + q;
  float best = g[0]; int bi = 0;
  #pragma unroll
  for (int c = 1; c < 21; c++) {
    float v = g[(long)c * 9216];
    if (v > best) { best = v; bi = c; }
  }
  lab[p] = (signed char)bi;
}

__global__ void k_em(const signed char* __restrict__ lab, signed char* __restrict__ em) {
  int p = blockIdx.x * 256 + threadIdx.x;
  int n = p / 9216, q = p - n * 9216, y = q / 96, x = q - y * 96;
  const signed char* L = lab + n * 9216;
  signed char l0 = L[q];
  bool uni = true;
  for (int dy = -2; dy <= 2; dy++) {
    int yy = y + dy; if (yy < 0 || yy > 95) continue;
    for (int dx = -2; dx <= 2; dx++) {
      int xx = x + dx; if (xx < 0 || xx > 95) continue;
      uni = uni && (L[yy * 96 + xx] == l0);
    }
  }
  em[p] = uni ? l0 : (signed char)-1;
}

// ---------------------------------------------------------------------------
// objs from featT (bf16): per-block LDS accumulator + class-presence flags
// ---------------------------------------------------------------------------
__global__ __launch_bounds__(256)
void k_objsT(const unsigned short* __restrict__ featT, const signed char* __restrict__ em,
             float* __restrict__ objs) {
  __shared__ float part[21 * 512];
  __shared__ signed char emL[256];
  __shared__ int pres[21];
  const int b = blockIdx.x;          // 288
  const int n = b / 36;
  const int px0 = (b - n * 36) * 256;
  const int tid = threadIdx.x;
  for (int i = tid; i < 21 * 512; i += 256) part[i] = 0.f;
  if (tid < 21) pres[tid] = 0;
  emL[tid] = em[n * 9216 + px0 + tid];
  __syncthreads();
  const unsigned short* base = featT + ((long)n * 9216 + px0) * 512 + tid * 2;
  for (int px = 0; px < 256; px++) {
    const int c0 = emL[px];
    if (c0 >= 0) {
      if (tid == 0) pres[c0] = 1;
      unsigned int v = *(const unsigned int*)&base[(long)px * 512];
      atomicAdd(&part[c0 * 512 + tid * 2], bf2f((unsigned short)(v & 0xffff)));
      atomicAdd(&part[c0 * 512 + tid * 2 + 1], bf2f((unsigned short)(v >> 16)));
    }
  }
  __syncthreads();
  for (int i = tid; i < 21 * 512; i += 256) {
    const int c = i >> 9;
    if (pres[c]) atomicAdd(&objs[(long)n * 21 * 512 + i], part[i] * (1.0f / 9216.0f));
  }
}

__global__ void k_o2(const float* __restrict__ objs, float* __restrict__ o2) {
  int nc = blockIdx.x;  // 168
  int lane = threadIdx.x;
  const float* o = objs + (long)nc * 512;
  float s = 0.f;
  for (int f = lane; f < 512; f += 64) { float v = o[f]; s += v * v; }
  #pragma unroll
  for (int off = 32; off; off >>= 1) s += __shfl_down(s, off);
  if (lane == 0) o2[nc] = s;
}

// objs_c[n][32][512] bf16, rows >=21 zero (MFMA A-operand for k_dist)
__global__ void k_objsbf(const float* __restrict__ objs, unsigned short* __restrict__ oc) {
  int i = blockIdx.x * 256 + threadIdx.x;  // 8*32*512 = 131072
  int n = i / (32 * 512); int r = i - n * 32 * 512;
  int c = r >> 9, f = r & 511;
  oc[i] = (c < 21) ? f2bf(objs[((long)n * 21 + c) * 512 + f]) : (unsigned short)0;
}

// ---------------------------------------------------------------------------
// dist via MFMA (verified R4 version)
// ---------------------------------------------------------------------------
__global__ __launch_bounds__(256)
void k_dist_mfma(const unsigned short* __restrict__ featT,
                 const unsigned short* __restrict__ objs_c,
                 const float* __restrict__ o2, float* __restrict__ dist) {
  const int n = blockIdx.y;
  const int w = threadIdx.x >> 6, lane = threadIdx.x & 63;
  const int lrow = lane & 15, kg = lane >> 4;
  const int px = blockIdx.x * 64 + w * 16 + lrow;   // grid.x = 144
  const unsigned short* fb = featT + ((long)n * 9216 + px) * 512 + kg * 8;
  const unsigned short* a0p = objs_c + ((long)n * 32 + lrow) * 512 + kg * 8;
  const unsigned short* a1p = a0p + 16 * 512;
  f32x4 acc0 = {0.f, 0.f, 0.f, 0.f}, acc1 = {0.f, 0.f, 0.f, 0.f};
  float x2 = 0.f;
  #pragma unroll
  for (int s = 0; s < 16; s++) {
    const short8 b = *(const short8*)&fb[s * 32];
    const short8 a0 = *(const short8*)&a0p[s * 32];
    const short8 a1 = *(const short8*)&a1p[s * 32];
    acc0 = __builtin_amdgcn_mfma_f32_16x16x32_bf16(a0, b, acc0, 0, 0, 0);
    acc1 = __builtin_amdgcn_mfma_f32_16x16x32_bf16(a1, b, acc1, 0, 0, 0);
    #pragma unroll
    for (int j = 0; j < 8; j++) { float v = bf2f((unsigned short)b[j]); x2 += v * v; }
  }
  x2 += __shfl_xor(x2, 16); x2 += __shfl_xor(x2, 32);  // full ||x_px||^2
  float cd[8], mx = -1e30f;
  #pragma unroll
  for (int r = 0; r < 4; r++) {
    const int c = kg * 4 + r;
    float d2 = x2 + o2[n * 21 + c] - 2.f * acc0[r];
    cd[r] = sqrtf(fmaxf(d2, 0.f)); mx = fmaxf(mx, cd[r]);
  }
  #pragma unroll
  for (int r = 0; r < 4; r++) {
    const int c = 16 + kg * 4 + r;
    if (c < 21) {
      float d2 = x2 + o2[n * 21 + c] - 2.f * acc1[r];
      cd[4 + r] = sqrtf(fmaxf(d2, 0.f)); mx = fmaxf(mx, cd[4 + r]);
    } else cd[4 + r] = -1e30f;
  }
  mx = fmaxf(mx, __shfl_xor(mx, 16)); mx = fmaxf(mx, __shfl_xor(mx, 32));
  float sum = 0.f;
  #pragma unroll
  for (int k = 0; k < 8; k++) {
    cd[k] = (cd[k] > -1e29f) ? __expf(cd[k] - mx) : 0.f;
    sum += cd[k];
  }
  sum += __shfl_xor(sum, 16); sum += __shfl_xor(sum, 32);
  const float inv = 1.f / sum;
  #pragma unroll
  for (int r = 0; r < 4; r++)
    dist[((long)n * 21 + kg * 4 + r) * 9216 + px] = 1.f - cd[r] * inv;
  #pragma unroll
  for (int r = 0; r < 4; r++) {
    const int c = 16 + kg * 4 + r;
    if (c < 21) dist[((long)n * 21 + c) * 9216 + px] = 1.f - cd[4 + r] * inv;
  }
}

// fusion (verified R4 version)
__global__ __launch_bounds__(256)
void k_fusion(const unsigned short* __restrict__ featT, const signed char* __restrict__ em,
              const float* __restrict__ dist, const float* __restrict__ objs,
              unsigned short* __restrict__ fuP) {
  __shared__ float ob[21 * 512];
  __shared__ float dl[64][21];
  __shared__ signed char eml[64];
  const int blk = blockIdx.x;  // 1152
  const int n = blk / 144;
  const int p0 = (blk - n * 144) * 64;
  const int tid = threadIdx.x;
  for (int i = tid; i < 21 * 512; i += 256) ob[i] = objs[(long)n * 21 * 512 + i];
  for (int i = tid; i < 64 * 21; i += 256) {
    int px = i & 63, c = i >> 6;
    dl[px][c] = dist[((long)n * 21 + c) * 9216 + p0 + px];
  }
  if (tid < 64) eml[tid] = em[n * 9216 + p0 + tid];
  __syncthreads();
  const int px = tid & 63;
  const int fg = (tid >> 6) * 8;
  const int q = p0 + px;
  const int y = q / 96, x = q - y * 96;
  unsigned short* dst = fuP + (((long)n * 98 + y + 1) * 98 + (x + 1)) * 512;
  const bool t = eml[px] < 0;
  const unsigned short* srcT = featT + ((long)n * 9216 + q) * 512;
  for (int f0 = 0; f0 < 512; f0 += 32) {
    short8 o;
    const short8 fvv = *(const short8*)&srcT[f0 + fg];
    #pragma unroll
    for (int j = 0; j < 8; j++) {
      const int f = f0 + fg + j;
      float fv = bf2f((unsigned short)fvv[j]);
      if (t) {
        float of = 0.f;
        #pragma unroll
        for (int c = 0; c < 21; c++) of += dl[px][c] * ob[c * 512 + f];
        fv = 0.1f * fv + 0.9f * of;
      }
      o[j] = (short)f2bf(fv);
    }
    *(short8*)&dst[fg] = o;
    dst += 32;
  }
}

// ---------------------------------------------------------------------------
// conv1: implicit-GEMM 3x3, 128x128 tile, BK=32, 4 waves.
// NEW: 4-buffer rotation, prefetch depth 3, counted vmcnt(8) (peel 4/0).
// Iteration: [vmcnt; barrier; kstep(s%4); stage(s+3)]
// ---------------------------------------------------------------------------
template <int CIN, int NK>
__global__ __launch_bounds__(256)
void conv3x3_gemm(const unsigned short* __restrict__ inP,
                  const unsigned short* __restrict__ wT,
                  const float* __restrict__ scale, const float* __restrict__ bias,
                  unsigned short* __restrict__ out,
                  int Hout, int Wout, int Hp, int Wp, int COUT, int nbN) {
  __shared__ unsigned short ldsA[4][4096];
  __shared__ unsigned short ldsB[4][4096];
  const int tid = threadIdx.x;
  const int chunk = gridDim.x >> 3;
  const int bid = (blockIdx.x & 7) * chunk + (blockIdx.x >> 3);
  const int mb = bid / nbN, nb = bid - mb * nbN;
  const int bm0 = mb * 128, bn0 = nb * 128;
  const int KT = 9 * CIN;
  const int HWo = Hout * Wout;

  const int rA = tid >> 2;
  const int ch8 = (((tid & 3) ^ ((tid >> 3) & 3)) * 8);
  const int m0 = bm0 + rA, m1 = m0 + 64;
  const int n0 = m0 / HWo; const int q0 = m0 - n0 * HWo;
  const int y0 = q0 / Wout, x0 = q0 - y0 * Wout;
  const int n1 = m1 / HWo; const int q1 = m1 - n1 * HWo;
  const int y1 = q1 / Wout, x1 = q1 - y1 * Wout;
  const unsigned short* gA0 = inP + ((long)(n0 * Hp + y0) * Wp + x0) * CIN + ch8;
  const unsigned short* gA1 = inP + ((long)(n1 * Hp + y1) * Wp + x1) * CIN + ch8;
  const unsigned short* gB0 = wT + (long)(bn0 + rA) * KT + ch8;
  const unsigned short* gB1 = wT + (long)(bn0 + rA + 64) * KT + ch8;

  const int lane = tid & 63;
  const int wv = tid >> 6;
  const int wr = wv >> 1, wc = wv & 1;
  const int lrow = lane & 15, kg = lane >> 4;
  const int arow = wr * 64 + lrow;
  const int aoff = arow * 32 + (kg ^ ((arow >> 1) & 3)) * 8;
  const int brow = wc * 64 + lrow;
  const int boff = brow * 32 + (kg ^ ((brow >> 1) & 3)) * 8;

  f32x4 acc[4][4];
  const f32x4 zero = {0.f, 0.f, 0.f, 0.f};
  #pragma unroll
  for (int i = 0; i < 4; i++)
    #pragma unroll
    for (int j = 0; j < 4; j++) acc[i][j] = zero;

  auto stage = [&](int b, int s) {
    const int cblk = s / 9;            // s = cblk*9 + t  (tap-fastest)
    const int t = s - cblk * 9;
    const int ty = t / 3, tx = t - ty * 3;
    const long offA = (long)(ty * Wp + tx) * CIN + cblk * 32;
    gload16(&ldsA[b][tid * 8], gA0 + offA);
    gload16(&ldsA[b][2048 + tid * 8], gA1 + offA);
    const long k0 = (long)s * 32;
    gload16(&ldsB[b][tid * 8], gB0 + k0);
    gload16(&ldsB[b][2048 + tid * 8], gB1 + k0);
  };

  auto kstep = [&](int rd) {
    const unsigned short* A = ldsA[rd];
    const unsigned short* B = ldsB[rd];
    short8 af[4], bfr[4];
    #pragma unroll
    for (int i = 0; i < 4; i++) af[i] = *(const short8*)&A[aoff + i * 512];
    #pragma unroll
    for (int j = 0; j < 4; j++) bfr[j] = *(const short8*)&B[boff + j * 512];
    __builtin_amdgcn_s_setprio(1);
    #pragma unroll
    for (int i = 0; i < 4; i++)
      #pragma unroll
      for (int j = 0; j < 4; j++)
        acc[i][j] = __builtin_amdgcn_mfma_f32_16x16x32_bf16(af[i], bfr[j], acc[i][j], 0, 0, 0);
    __builtin_amdgcn_s_setprio(0);
  };

  // prologue: 3 stages in flight
  stage(0, 0);
  stage(1, 1);
  stage(2, 2);
  for (int s = 0; s < NK; ++s) {
    if (s <= NK - 3)
      asm volatile("s_waitcnt vmcnt(8)" ::: "memory");   // stage(s) landed; s+1,s+2 in flight
    else if (s == NK - 2)
      asm volatile("s_waitcnt vmcnt(4)" ::: "memory");
    else
      asm volatile("s_waitcnt vmcnt(0)" ::: "memory");
    __builtin_amdgcn_s_barrier();                        // all waves' landed
    asm volatile("" ::: "memory");
    kstep(s & 3);
    if (s + 3 < NK) stage((s + 3) & 3, s + 3);
  }

  #pragma unroll
  for (int i = 0; i < 4; i++) {
    const int row = bm0 + wr * 64 + i * 16 + kg * 4;
    #pragma unroll
    for (int j = 0; j < 4; j++) {
      const int col = bn0 + wc * 64 + j * 16 + lrow;
      const float sc = scale[col], bi = bias[col];
      #pragma unroll
      for (int r = 0; r < 4; r++) {
        float v = acc[i][j][r] * sc + bi;
        v = v > 0.f ? v : 0.f;
        out[(long)(row + r) * COUT + col] = f2bf(v);
      }
    }
  }
}

// ---------------------------------------------------------------------------
// conv2 + fused 1x1 conv3 + bias + softmax.  Main loop = R7 3-buffer with
// CORRECTED vmcnt(4) (stage = 4 loads; only stage(s+1) outstanding past the
// wait).  Epilogue: relu'd bf16 tile -> LDS (slot-XOR swizzled), then the
// verified k_conv3_mfma pattern per wave (w3b = A, h-tile = B), softmax via
// shfl_xor, write NCHW fp32 out directly.  Kills h3 (150 MB traffic) and the
// separate kernel.
// ---------------------------------------------------------------------------
__global__ __launch_bounds__(256)
void conv2_fused(const unsigned short* __restrict__ inP,
                 const unsigned short* __restrict__ wT,
                 const float* __restrict__ scale, const float* __restrict__ bias,
                 const unsigned short* __restrict__ w3b, const float* __restrict__ b3,
                 float* __restrict__ out) {
  constexpr int CIN = 256, NK = 72;
  constexpr int Wout = 192, Hp = 194, Wp = 194;
  constexpr int HWo = 192 * 192;
  constexpr int KT = 9 * CIN;
  __shared__ unsigned short pool[6 * 4096];   // 48KB: 3xA @0, 3xB @12288; h-tile reuses @0
  const int tid = threadIdx.x;
  const int chunk = gridDim.x >> 3;
  const int bid = (blockIdx.x & 7) * chunk + (blockIdx.x >> 3);
  const int bm0 = bid * 128;                  // nbN = 1, bn0 = 0

  const int rA = tid >> 2;
  const int ch8 = (((tid & 3) ^ ((tid >> 3) & 3)) * 8);
  const int m0 = bm0 + rA, m1 = m0 + 64;
  const int n0 = m0 / HWo; const int q0 = m0 - n0 * HWo;
  const int y0 = q0 / Wout, x0 = q0 - y0 * Wout;
  const int n1 = m1 / HWo; const int q1 = m1 - n1 * HWo;
  const int y1 = q1 / Wout, x1 = q1 - y1 * Wout;
  const unsigned short* gA0 = inP + ((long)(n0 * Hp + y0) * Wp + x0) * CIN + ch8;
  const unsigned short* gA1 = inP + ((long)(n1 * Hp + y1) * Wp + x1) * CIN + ch8;
  const unsigned short* gB0 = wT + (long)rA * KT + ch8;
  const unsigned short* gB1 = wT + (long)(rA + 64) * KT + ch8;

  const int lane = tid & 63;
  const int wv = tid >> 6;
  const int wr = wv >> 1, wc = wv & 1;
  const int lrow = lane & 15, kg = lane >> 4;
  const int arow = wr * 64 + lrow;
  const int aoff = arow * 32 + (kg ^ ((arow >> 1) & 3)) * 8;
  const int brow = wc * 64 + lrow;
  const int boff = brow * 32 + (kg ^ ((brow >> 1) & 3)) * 8;

  f32x4 acc[4][4];
  const f32x4 zero = {0.f, 0.f, 0.f, 0.f};
  #pragma unroll
  for (int i = 0; i < 4; i++)
    #pragma unroll
    for (int j = 0; j < 4; j++) acc[i][j] = zero;

  auto stage = [&](int b, int s) {
    const int cblk = s / 9;
    const int t = s - cblk * 9;
    const int ty = t / 3, tx = t - ty * 3;
    const long offA = (long)(ty * Wp + tx) * CIN + cblk * 32;
    gload16(&pool[b * 4096 + tid * 8], gA0 + offA);
    gload16(&pool[b * 4096 + 2048 + tid * 8], gA1 + offA);
    const long k0 = (long)s * 32;
    gload16(&pool[12288 + b * 4096 + tid * 8], gB0 + k0);
    gload16(&pool[12288 + b * 4096 + 2048 + tid * 8], gB1 + k0);
  };

  auto kstep = [&](int rd) {
    const unsigned short* A = &pool[rd * 4096];
    const unsigned short* B = &pool[12288 + rd * 4096];
    short8 af[4], bfr[4];
    #pragma unroll
    for (int i = 0; i < 4; i++) af[i] = *(const short8*)&A[aoff + i * 512];
    #pragma unroll
    for (int j = 0; j < 4; j++) bfr[j] = *(const short8*)&B[boff + j * 512];
    __builtin_amdgcn_s_setprio(1);
    #pragma unroll
    for (int i = 0; i < 4; i++)
      #pragma unroll
      for (int j = 0; j < 4; j++)
        acc[i][j] = __builtin_amdgcn_mfma_f32_16x16x32_bf16(af[i], bfr[j], acc[i][j], 0, 0, 0);
    __builtin_amdgcn_s_setprio(0);
  };

  stage(0, 0);
  stage(1, 1);
  int rd = 0;
  for (int s = 0; s < NK; ++s) {
    if (s < NK - 1)
      asm volatile("s_waitcnt vmcnt(4)" ::: "memory");   // stage(s) landed; s+1 in flight
    else
      asm volatile("s_waitcnt vmcnt(0)" ::: "memory");
    __builtin_amdgcn_s_barrier();
    asm volatile("" ::: "memory");
    kstep(rd);
    if (s + 2 < NK) stage((rd + 2 >= 3) ? rd - 1 : rd + 2, s + 2);
    rd = (rd == 2) ? 0 : rd + 1;
  }

  // ---- fused epilogue: BN+ReLU -> LDS h-tile [128px][128ch], slot-swizzled
  asm volatile("s_waitcnt lgkmcnt(0)" ::: "memory");
  __builtin_amdgcn_s_barrier();
  asm volatile("" ::: "memory");
  #pragma unroll
  for (int j = 0; j < 4; j++) {
    const int ch = wc * 64 + j * 16 + lrow;
    const float sc = scale[ch], bi = bias[ch];
    #pragma unroll
    for (int i = 0; i < 4; i++) {
      const int pxb = wr * 64 + i * 16 + kg * 4;
      #pragma unroll
      for (int r = 0; r < 4; r++) {
        const int px = pxb + r;
        float v = acc[i][j][r] * sc + bi;
        v = v > 0.f ? v : 0.f;
        pool[px * 128 + (ch ^ ((px & 7) << 3))] = f2bf(v);
      }
    }
  }
  asm volatile("s_waitcnt lgkmcnt(0)" ::: "memory");
  __builtin_amdgcn_s_barrier();
  asm volatile("" ::: "memory");

  // ---- conv3 (21x128) + softmax, 32 px per wave (verified k_conv3_mfma map)
  #pragma unroll
  for (int g = 0; g < 2; g++) {
    const int px = wv * 32 + g * 16 + lrow;
    f32x4 acc0 = {0.f, 0.f, 0.f, 0.f}, acc1 = {0.f, 0.f, 0.f, 0.f};
    #pragma unroll
    for (int s = 0; s < 4; s++) {
      const int ch0 = s * 32 + kg * 8;
      const short8 b = *(const short8*)&pool[px * 128 + (ch0 ^ ((px & 7) << 3))];
      const short8 a0 = *(const short8*)&w3b[lrow * 128 + ch0];
      const short8 a1 = *(const short8*)&w3b[(16 + lrow) * 128 + ch0];
      acc0 = __builtin_amdgcn_mfma_f32_16x16x32_bf16(a0, b, acc0, 0, 0, 0);
      acc1 = __builtin_amdgcn_mfma_f32_16x16x32_bf16(a1, b, acc1, 0, 0, 0);
    }
    float lg[8], mx = -1e30f;
    #pragma unroll
    for (int r = 0; r < 4; r++) {
      lg[r] = acc0[r] + b3[kg * 4 + r];
      mx = fmaxf(mx, lg[r]);
    }
    #pragma unroll
    for (int r = 0; r < 4; r++) {
      const int c = 16 + kg * 4 + r;
      if (c < 21) { lg[4 + r] = acc1[r] + b3[c]; mx = fmaxf(mx, lg[4 + r]); }
      else lg[4 + r] = -1e30f;
    }
    mx = fmaxf(mx, __shfl_xor(mx, 16)); mx = fmaxf(mx, __shfl_xor(mx, 32));
    float sum = 0.f;
    #pragma unroll
    for (int k = 0; k < 8; k++) {
      lg[k] = (lg[k] > -1e29f) ? __expf(lg[k] - mx) : 0.f;
      sum += lg[k];
    }
    sum += __shfl_xor(sum, 16); sum += __shfl_xor(sum, 32);
    const float inv = 1.f / sum;
    const int m = bm0 + px;
    const int n = m / HWo;
    const int q = m - n * HWo;
    #pragma unroll
    for (int r = 0; r < 4; r++)
      out[((long)n * 21 + kg * 4 + r) * (long)HWo + q] = lg[r] * inv;
    #pragma unroll
    for (int r = 0; r < 4; r++) {
      const int c = 16 + kg * 4 + r;
      if (c < 21) out[((long)n * 21 + c) * (long)HWo + q] = lg[4 + r] * inv;
    }
  }
}

// ---------------------------------------------------------------------------
// jax bilinear x2 -> padded h2P[8][194][194][256]
// ---------------------------------------------------------------------------
__global__ void k_upsample(const unsigned short* __restrict__ h1,
                           unsigned short* __restrict__ h2P) {
  const int idx = blockIdx.x * 256 + threadIdx.x;  // 8*192*192*32
  const int c8 = (idx & 31) * 8;
  const int p = idx >> 5;
  const int n = p / 36864; const int rr = p - n * 36864;
  const int Y = rr / 192, X = rr - Y * 192;
  const int ky = Y >> 1, kx = X >> 1;
  int yA, yB, xA, xB; float wyA, wyB, wxA, wxB;
  if ((Y & 1) == 0) { yA = ky > 0 ? ky - 1 : 0; yB = ky; wyA = 0.25f; wyB = 0.75f; }
  else { yA = ky; yB = ky < 95 ? ky + 1 : 95; wyA = 0.75f; wyB = 0.25f; }
  if ((X & 1) == 0) { xA = kx > 0 ? kx - 1 : 0; xB = kx; wxA = 0.25f; wxB = 0.75f; }
  else { xA = kx; xB = kx < 95 ? kx + 1 : 95; wxA = 0.75f; wxB = 0.25f; }
  const unsigned short* hb = h1 + (long)n * 96 * 96 * 256 + c8;
  const short8 vaa = *(const short8*)&hb[((long)yA * 96 + xA) * 256];
  const short8 vab = *(const short8*)&hb[((long)yA * 96 + xB) * 256];
  const short8 vba = *(const short8*)&hb[((long)yB * 96 + xA) * 256];
  const short8 vbb = *(const short8*)&hb[((long)yB * 96 + xB) * 256];
  short8 o;
  #pragma unroll
  for (int j = 0; j < 8; j++) {
    float v = wyA * (wxA * bf2f((unsigned short)vaa[j]) + wxB * bf2f((unsigned short)vab[j])) +
              wyB * (wxA * bf2f((unsigned short)vba[j]) + wxB * bf2f((unsigned short)vbb[j]));
    o[j] = (short)f2bf(v);
  }
  *(short8*)&h2P[(((long)n * 194 + Y + 1) * 194 + X + 1) * 256 + c8] = o;
}

// ---------------------------------------------------------------------------
extern "C" void kernel_launch(void* const* d_in, const int* in_sizes, int n_in,
                              void* d_out, int out_size, void* d_ws, size_t ws_size,
                              hipStream_t stream) {
  const float* feature = (const float*)d_in[0];
  const float* gp = (const float*)d_in[1];
  const float* w1 = (const float*)d_in[2];
  const float* g1 = (const float*)d_in[3];
  const float* b1 = (const float*)d_in[4];
  const float* m1 = (const float*)d_in[5];
  const float* v1 = (const float*)d_in[6];
  const float* w2 = (const float*)d_in[7];
  const float* g2 = (const float*)d_in[8];
  const float* b2 = (const float*)d_in[9];
  const float* m2 = (const float*)d_in[10];
  const float* v2 = (const float*)d_in[11];
  const float* w3 = (const float*)d_in[12];
  const float* b3 = (const float*)d_in[13];
  float* out = (float*)d_out;

  char* ws = (char*)d_ws;
  size_t off = 0;
  auto alloc = [&](size_t bytes) -> void* {
    void* p = ws + off;
    off += (bytes + 255) & ~(size_t)255;
    return p;
  };
  signed char* lab = (signed char*)alloc(73728);
  signed char* em = (signed char*)alloc(73728);
  float* objs = (float*)alloc(8 * 21 * 512 * 4);
  float* o2 = (float*)alloc(168 * 4);
  unsigned short* objs_c = (unsigned short*)alloc((size_t)8 * 32 * 512 * 2);
  float* dist = (float*)alloc((size_t)8 * 21 * 9216 * 4);
  unsigned short* w1t = (unsigned short*)alloc((size_t)256 * 4608 * 2);
  unsigned short* w2t = (unsigned short*)alloc((size_t)128 * 2304 * 2);
  unsigned short* w3b = (unsigned short*)alloc((size_t)32 * 128 * 2);
  float* s1 = (float*)alloc(256 * 4);
  float* bb1 = (float*)alloc(256 * 4);
  float* s2 = (float*)alloc(128 * 4);
  float* bb2 = (float*)alloc(128 * 4);
  const size_t fuP_bytes = (size_t)8 * 98 * 98 * 512 * 2;    // 78.7 MB
  unsigned short* fuP = (unsigned short*)alloc(fuP_bytes);
  const size_t h1_bytes = (size_t)8 * 96 * 96 * 256 * 2;     // 37.7 MB
  unsigned short* h1 = (unsigned short*)alloc(h1_bytes);
  const size_t h2P_bytes = (size_t)8 * 194 * 194 * 256 * 2;  // 154.1 MB
  unsigned short* h2P = (unsigned short*)alloc(h2P_bytes);
  unsigned short* featT = h2P;   // featT (75.5 MB) dead before border(h2P)/upsample

  if (off > ws_size) return;  // workspace too small — fail loudly via wrong output

  k_prepbn<<<1, 256, 0, stream>>>(g1, b1, m1, v1, g2, b2, m2, v2, s1, bb1, s2, bb2);
  k_prepw1<<<4608, 256, 0, stream>>>(w1, w1t);
  k_prepw2<<<1152, 256, 0, stream>>>(w2, w2t);
  k_prepw3<<<16, 256, 0, stream>>>(w3, w3b);

  k_border<98, 98, 512><<<777, 256, 0, stream>>>(fuP);
  hipMemsetAsync(objs, 0, 8 * 21 * 512 * 4, stream);

  k_labels<<<288, 256, 0, stream>>>(gp, lab);
  k_em<<<288, 256, 0, stream>>>(lab, em);
  k_featT<<<dim3(288, 4), 256, 0, stream>>>(feature, featT);
  k_objsT<<<288, 256, 0, stream>>>(featT, em, objs);
  k_o2<<<168, 64, 0, stream>>>(objs, o2);
  k_objsbf<<<512, 256, 0, stream>>>(objs, objs_c);
  k_dist_mfma<<<dim3(144, 8), 256, 0, stream>>>(featT, objs_c, o2, dist);
  k_fusion<<<1152, 256, 0, stream>>>(featT, em, dist, objs, fuP);

  conv3x3_gemm<512, 144><<<1152, 256, 0, stream>>>(fuP, w1t, s1, bb1, h1,
                                                   96, 96, 98, 98, 256, 2);
  // featT (aliasing h2P) is dead from here on
  k_border<194, 194, 256><<<772, 256, 0, stream>>>(h2P);
  k_upsample<<<36864, 256, 0, stream>>>(h1, h2P);
  conv2_fused<<<2304, 256, 0, stream>>>(h2P, w2t, s2, bb2, w3b, b3, out);
}

// Round 9
// 765.339 us; speedup vs baseline: 1.0459x; 1.0459x over previous
//
#include <hip/hip_runtime.h>
#include <cstdint>
#include <cstddef>

typedef __attribute__((ext_vector_type(4))) float f32x4;
typedef __attribute__((ext_vector_type(8))) short short8;

__device__ __forceinline__ float bf2f(unsigned short u) {
  union { unsigned int i; float f; } x; x.i = ((unsigned int)u) << 16; return x.f;
}
__device__ __forceinline__ unsigned short f2bf(float f) {
  union { float f; unsigned int i; } x; x.f = f;
  unsigned int r = x.i + 0x7fffu + ((x.i >> 16) & 1u);
  return (unsigned short)(r >> 16);
}
__device__ __forceinline__ void gload16(unsigned short* lds, const unsigned short* g) {
  __builtin_amdgcn_global_load_lds(
      (const __attribute__((address_space(1))) unsigned int*)g,
      (__attribute__((address_space(3))) unsigned int*)lds, 16, 0, 0);
}

// ---------------------------------------------------------------------------
// prep kernels
// ---------------------------------------------------------------------------
__global__ void k_prepbn(const float* __restrict__ g1, const float* __restrict__ b1,
                         const float* __restrict__ m1, const float* __restrict__ v1,
                         const float* __restrict__ g2, const float* __restrict__ b2,
                         const float* __restrict__ m2, const float* __restrict__ v2,
                         float* __restrict__ s1, float* __restrict__ bb1,
                         float* __restrict__ s2, float* __restrict__ bb2) {
  int i = threadIdx.x;
  if (i < 256) { float s = g1[i] * rsqrtf(v1[i] + 1e-5f); s1[i] = s; bb1[i] = b1[i] - m1[i] * s; }
  if (i < 128) { float s = g2[i] * rsqrtf(v2[i] + 1e-5f); s2[i] = s; bb2[i] = b2[i] - m2[i] * s; }
}

__global__ void k_prepw1(const float* __restrict__ w, unsigned short* __restrict__ wt) {
  int i = blockIdx.x * 256 + threadIdx.x;  // 256*4608
  int o = i / 4608, k = i - o * 4608;
  int cblk = k / 288, r = k - cblk * 288;
  int t = r >> 5, cl = r & 31;
  int ci = cblk * 32 + cl;
  int ty = t / 3, tx = t - ty * 3;
  wt[i] = f2bf(w[((o * 512 + ci) * 3 + ty) * 3 + tx]);
}
__global__ void k_prepw2(const float* __restrict__ w, unsigned short* __restrict__ wt) {
  int i = blockIdx.x * 256 + threadIdx.x;  // 128*2304
  int o = i / 2304, k = i - o * 2304;
  int cblk = k / 288, r = k - cblk * 288;
  int t = r >> 5, cl = r & 31;
  int ci = cblk * 32 + cl;
  int ty = t / 3, tx = t - ty * 3;
  wt[i] = f2bf(w[((o * 256 + ci) * 3 + ty) * 3 + tx]);
}
// w3b[32][128] bf16, rows >=21 zero
__global__ void k_prepw3(const float* __restrict__ w3, unsigned short* __restrict__ w3b) {
  int i = blockIdx.x * 256 + threadIdx.x;  // 4096
  int c = i >> 7, k = i & 127;
  w3b[i] = (c < 21) ? f2bf(w3[c * 128 + k]) : (unsigned short)0;
}

// zero the 1-px halo ring of a padded NHWC tensor
template <int HP, int WP, int C>
__global__ void k_border(unsigned short* __restrict__ p) {
  const int B = 2 * WP + 2 * (HP - 2);
  const int total = 8 * B * (C / 8);
  int i = blockIdx.x * 256 + threadIdx.x;
  if (i >= total) return;
  const int cg = i % (C / 8);
  int b = i / (C / 8);
  const int n = b / B; b -= n * B;
  int y, x;
  if (b < WP) { y = 0; x = b; }
  else if (b < 2 * WP) { y = HP - 1; x = b - WP; }
  else { int r = b - 2 * WP; y = 1 + (r >> 1); x = (r & 1) ? (WP - 1) : 0; }
  short8 z = {0, 0, 0, 0, 0, 0, 0, 0};
  *(short8*)&p[(((long)n * HP + y) * WP + x) * C + cg * 8] = z;
}

// ---------------------------------------------------------------------------
// feat_T[n][px][512] bf16 from feature[n][512][px] fp32 (coalesced reads)
// ---------------------------------------------------------------------------
__global__ __launch_bounds__(256)
void k_featT(const float* __restrict__ feat, unsigned short* __restrict__ featT) {
  const int g = blockIdx.x * 256 + threadIdx.x;  // 73728 px total
  const int n = g / 9216, p = g - n * 9216;
  const int fg0 = blockIdx.y * 16;               // grid.y = 4
  const float* src = feat + (long)n * 512 * 9216 + p;
  unsigned short* dst = featT + ((long)n * 9216 + p) * 512;
  for (int fg = fg0; fg < fg0 + 16; fg++) {
    short8 o;
    #pragma unroll
    for (int j = 0; j < 8; j++) o[j] = (short)f2bf(src[(long)(fg * 8 + j) * 9216]);
    *(short8*)&dst[fg * 8] = o;
  }
}

// ---------------------------------------------------------------------------
// labels / morphology
// ---------------------------------------------------------------------------
__global__ void k_labels(const float* __restrict__ gp, signed char* __restrict__ lab) {
  int p = blockIdx.x * 256 + threadIdx.x;  // 73728
  int n = p / 9216, q = p - n * 9216;
  const float* g = gp + (long)n * 21 * 9216 + q;
  float best = g[0]; int bi = 0;
  #pragma unroll
  for (int c = 1; c < 21; c++) {
    float v = g[(long)c * 9216];
    if (v > best) { best = v; bi = c; }
  }
  lab[p] = (signed char)bi;
}

__global__ void k_em(const signed char* __restrict__ lab, signed char* __restrict__ em) {
  int p = blockIdx.x * 256 + threadIdx.x;
  int n = p / 9216, q = p - n * 9216, y = q / 96, x = q - y * 96;
  const signed char* L = lab + n * 9216;
  signed char l0 = L[q];
  bool uni = true;
  for (int dy = -2; dy <= 2; dy++) {
    int yy = y + dy; if (yy < 0 || yy > 95) continue;
    for (int dx = -2; dx <= 2; dx++) {
      int xx = x + dx; if (xx < 0 || xx > 95) continue;
      uni = uni && (L[yy * 96 + xx] == l0);
    }
  }
  em[p] = uni ? l0 : (signed char)-1;
}

// ---------------------------------------------------------------------------
// objs from featT (bf16): per-block LDS accumulator + class-presence flags
// ---------------------------------------------------------------------------
__global__ __launch_bounds__(256)
void k_objsT(const unsigned short* __restrict__ featT, const signed char* __restrict__ em,
             float* __restrict__ objs) {
  __shared__ float part[21 * 512];
  __shared__ signed char emL[256];
  __shared__ int pres[21];
  const int b = blockIdx.x;          // 288
  const int n = b / 36;
  const int px0 = (b - n * 36) * 256;
  const int tid = threadIdx.x;
  for (int i = tid; i < 21 * 512; i += 256) part[i] = 0.f;
  if (tid < 21) pres[tid] = 0;
  emL[tid] = em[n * 9216 + px0 + tid];
  __syncthreads();
  const unsigned short* base = featT + ((long)n * 9216 + px0) * 512 + tid * 2;
  for (int px = 0; px < 256; px++) {
    const int c0 = emL[px];
    if (c0 >= 0) {
      if (tid == 0) pres[c0] = 1;
      unsigned int v = *(const unsigned int*)&base[(long)px * 512];
      atomicAdd(&part[c0 * 512 + tid * 2], bf2f((unsigned short)(v & 0xffff)));
      atomicAdd(&part[c0 * 512 + tid * 2 + 1], bf2f((unsigned short)(v >> 16)));
    }
  }
  __syncthreads();
  for (int i = tid; i < 21 * 512; i += 256) {
    const int c = i >> 9;
    if (pres[c]) atomicAdd(&objs[(long)n * 21 * 512 + i], part[i] * (1.0f / 9216.0f));
  }
}

// o2 + objs_c (bf16, rows >=21 zero) in one pass.  grid 256 = 8n x 32c, 64 thr
__global__ void k_objfin(const float* __restrict__ objs, float* __restrict__ o2,
                         unsigned short* __restrict__ oc) {
  const int b = blockIdx.x;
  const int n = b >> 5, c = b & 31;
  const int lane = threadIdx.x;
  unsigned short* dst = oc + ((long)n * 32 + c) * 512;
  if (c < 21) {
    const float* o = objs + ((long)n * 21 + c) * 512;
    float s = 0.f;
    for (int f = lane; f < 512; f += 64) {
      float v = o[f];
      s += v * v;
      dst[f] = f2bf(v);
    }
    #pragma unroll
    for (int off = 32; off; off >>= 1) s += __shfl_down(s, off);
    if (lane == 0) o2[n * 21 + c] = s;
  } else {
    for (int f = lane; f < 512; f += 64) dst[f] = 0;
  }
}

// ---------------------------------------------------------------------------
// dist via MFMA (verified R4 version)
// ---------------------------------------------------------------------------
__global__ __launch_bounds__(256)
void k_dist_mfma(const unsigned short* __restrict__ featT,
                 const unsigned short* __restrict__ objs_c,
                 const float* __restrict__ o2, float* __restrict__ dist) {
  const int n = blockIdx.y;
  const int w = threadIdx.x >> 6, lane = threadIdx.x & 63;
  const int lrow = lane & 15, kg = lane >> 4;
  const int px = blockIdx.x * 64 + w * 16 + lrow;   // grid.x = 144
  const unsigned short* fb = featT + ((long)n * 9216 + px) * 512 + kg * 8;
  const unsigned short* a0p = objs_c + ((long)n * 32 + lrow) * 512 + kg * 8;
  const unsigned short* a1p = a0p + 16 * 512;
  f32x4 acc0 = {0.f, 0.f, 0.f, 0.f}, acc1 = {0.f, 0.f, 0.f, 0.f};
  float x2 = 0.f;
  #pragma unroll
  for (int s = 0; s < 16; s++) {
    const short8 b = *(const short8*)&fb[s * 32];
    const short8 a0 = *(const short8*)&a0p[s * 32];
    const short8 a1 = *(const short8*)&a1p[s * 32];
    acc0 = __builtin_amdgcn_mfma_f32_16x16x32_bf16(a0, b, acc0, 0, 0, 0);
    acc1 = __builtin_amdgcn_mfma_f32_16x16x32_bf16(a1, b, acc1, 0, 0, 0);
    #pragma unroll
    for (int j = 0; j < 8; j++) { float v = bf2f((unsigned short)b[j]); x2 += v * v; }
  }
  x2 += __shfl_xor(x2, 16); x2 += __shfl_xor(x2, 32);  // full ||x_px||^2
  float cd[8], mx = -1e30f;
  #pragma unroll
  for (int r = 0; r < 4; r++) {
    const int c = kg * 4 + r;
    float d2 = x2 + o2[n * 21 + c] - 2.f * acc0[r];
    cd[r] = sqrtf(fmaxf(d2, 0.f)); mx = fmaxf(mx, cd[r]);
  }
  #pragma unroll
  for (int r = 0; r < 4; r++) {
    const int c = 16 + kg * 4 + r;
    if (c < 21) {
      float d2 = x2 + o2[n * 21 + c] - 2.f * acc1[r];
      cd[4 + r] = sqrtf(fmaxf(d2, 0.f)); mx = fmaxf(mx, cd[4 + r]);
    } else cd[4 + r] = -1e30f;
  }
  mx = fmaxf(mx, __shfl_xor(mx, 16)); mx = fmaxf(mx, __shfl_xor(mx, 32));
  float sum = 0.f;
  #pragma unroll
  for (int k = 0; k < 8; k++) {
    cd[k] = (cd[k] > -1e29f) ? __expf(cd[k] - mx) : 0.f;
    sum += cd[k];
  }
  sum += __shfl_xor(sum, 16); sum += __shfl_xor(sum, 32);
  const float inv = 1.f / sum;
  #pragma unroll
  for (int r = 0; r < 4; r++)
    dist[((long)n * 21 + kg * 4 + r) * 9216 + px] = 1.f - cd[r] * inv;
  #pragma unroll
  for (int r = 0; r < 4; r++) {
    const int c = 16 + kg * 4 + r;
    if (c < 21) dist[((long)n * 21 + c) * 9216 + px] = 1.f - cd[4 + r] * inv;
  }
}

// fusion (verified R4 version)
__global__ __launch_bounds__(256)
void k_fusion(const unsigned short* __restrict__ featT, const signed char* __restrict__ em,
              const float* __restrict__ dist, const float* __restrict__ objs,
              unsigned short* __restrict__ fuP) {
  __shared__ float ob[21 * 512];
  __shared__ float dl[64][21];
  __shared__ signed char eml[64];
  const int blk = blockIdx.x;  // 1152
  const int n = blk / 144;
  const int p0 = (blk - n * 144) * 64;
  const int tid = threadIdx.x;
  for (int i = tid; i < 21 * 512; i += 256) ob[i] = objs[(long)n * 21 * 512 + i];
  for (int i = tid; i < 64 * 21; i += 256) {
    int px = i & 63, c = i >> 6;
    dl[px][c] = dist[((long)n * 21 + c) * 9216 + p0 + px];
  }
  if (tid < 64) eml[tid] = em[n * 9216 + p0 + tid];
  __syncthreads();
  const int px = tid & 63;
  const int fg = (tid >> 6) * 8;
  const int q = p0 + px;
  const int y = q / 96, x = q - y * 96;
  unsigned short* dst = fuP + (((long)n * 98 + y + 1) * 98 + (x + 1)) * 512;
  const bool t = eml[px] < 0;
  const unsigned short* srcT = featT + ((long)n * 9216 + q) * 512;
  for (int f0 = 0; f0 < 512; f0 += 32) {
    short8 o;
    const short8 fvv = *(const short8*)&srcT[f0 + fg];
    #pragma unroll
    for (int j = 0; j < 8; j++) {
      const int f = f0 + fg + j;
      float fv = bf2f((unsigned short)fvv[j]);
      if (t) {
        float of = 0.f;
        #pragma unroll
        for (int c = 0; c < 21; c++) of += dl[px][c] * ob[c * 512 + f];
        fv = 0.1f * fv + 0.9f * of;
      }
      o[j] = (short)f2bf(fv);
    }
    *(short8*)&dst[fg] = o;
    dst += 32;
  }
}

// ---------------------------------------------------------------------------
// conv1: implicit-GEMM 3x3, 128x128 tile, BK=32, 4 waves (R5 verbatim —
// measured best: 257us).  3-buffer LDS rotation, prefetch depth 2, dual
// s_barrier + counted vmcnt(8), tail peeled 4/0.
// ---------------------------------------------------------------------------
template <int CIN, int NK>
__global__ __launch_bounds__(256)
void conv3x3_gemm(const unsigned short* __restrict__ inP,
                  const unsigned short* __restrict__ wT,
                  const float* __restrict__ scale, const float* __restrict__ bias,
                  unsigned short* __restrict__ out,
                  int Hout, int Wout, int Hp, int Wp, int COUT, int nbN) {
  __shared__ unsigned short ldsA[3][4096];
  __shared__ unsigned short ldsB[3][4096];
  const int tid = threadIdx.x;
  const int chunk = gridDim.x >> 3;
  const int bid = (blockIdx.x & 7) * chunk + (blockIdx.x >> 3);
  const int mb = bid / nbN, nb = bid - mb * nbN;
  const int bm0 = mb * 128, bn0 = nb * 128;
  const int KT = 9 * CIN;
  const int HWo = Hout * Wout;

  const int rA = tid >> 2;
  const int ch8 = (((tid & 3) ^ ((tid >> 3) & 3)) * 8);
  const int m0 = bm0 + rA, m1 = m0 + 64;
  const int n0 = m0 / HWo; const int q0 = m0 - n0 * HWo;
  const int y0 = q0 / Wout, x0 = q0 - y0 * Wout;
  const int n1 = m1 / HWo; const int q1 = m1 - n1 * HWo;
  const int y1 = q1 / Wout, x1 = q1 - y1 * Wout;
  const unsigned short* gA0 = inP + ((long)(n0 * Hp + y0) * Wp + x0) * CIN + ch8;
  const unsigned short* gA1 = inP + ((long)(n1 * Hp + y1) * Wp + x1) * CIN + ch8;
  const unsigned short* gB0 = wT + (long)(bn0 + rA) * KT + ch8;
  const unsigned short* gB1 = wT + (long)(bn0 + rA + 64) * KT + ch8;

  const int lane = tid & 63;
  const int wv = tid >> 6;
  const int wr = wv >> 1, wc = wv & 1;
  const int lrow = lane & 15, kg = lane >> 4;
  const int arow = wr * 64 + lrow;
  const int aoff = arow * 32 + (kg ^ ((arow >> 1) & 3)) * 8;
  const int brow = wc * 64 + lrow;
  const int boff = brow * 32 + (kg ^ ((brow >> 1) & 3)) * 8;

  f32x4 acc[4][4];
  const f32x4 zero = {0.f, 0.f, 0.f, 0.f};
  #pragma unroll
  for (int i = 0; i < 4; i++)
    #pragma unroll
    for (int j = 0; j < 4; j++) acc[i][j] = zero;

  auto stage = [&](int b, int s) {
    const int cblk = s / 9;            // s = cblk*9 + t  (tap-fastest)
    const int t = s - cblk * 9;
    const int ty = t / 3, tx = t - ty * 3;
    const long offA = (long)(ty * Wp + tx) * CIN + cblk * 32;
    gload16(&ldsA[b][tid * 8], gA0 + offA);
    gload16(&ldsA[b][2048 + tid * 8], gA1 + offA);
    const long k0 = (long)s * 32;
    gload16(&ldsB[b][tid * 8], gB0 + k0);
    gload16(&ldsB[b][2048 + tid * 8], gB1 + k0);
  };

  auto kstep = [&](int rd) {
    const unsigned short* A = ldsA[rd];
    const unsigned short* B = ldsB[rd];
    short8 af[4], bfr[4];
    #pragma unroll
    for (int i = 0; i < 4; i++) af[i] = *(const short8*)&A[aoff + i * 512];
    #pragma unroll
    for (int j = 0; j < 4; j++) bfr[j] = *(const short8*)&B[boff + j * 512];
    __builtin_amdgcn_s_setprio(1);
    #pragma unroll
    for (int i = 0; i < 4; i++)
      #pragma unroll
      for (int j = 0; j < 4; j++)
        acc[i][j] = __builtin_amdgcn_mfma_f32_16x16x32_bf16(af[i], bfr[j], acc[i][j], 0, 0, 0);
    __builtin_amdgcn_s_setprio(0);
  };

  // prologue: 2 stages in flight
  stage(0, 0);
  stage(1, 1);
  int rd = 0, prev = 2;
  for (int s = 0; s < NK - 2; ++s) {
    __builtin_amdgcn_s_barrier();                    // barrier_A: buf[prev] free
    asm volatile("" ::: "memory");
    stage(prev, s + 2);
    asm volatile("s_waitcnt vmcnt(8)" ::: "memory"); // my buf[rd] loads landed
    __builtin_amdgcn_s_barrier();                    // barrier_B: all waves' landed
    asm volatile("" ::: "memory");
    kstep(rd);
    prev = rd; rd = (rd == 2) ? 0 : rd + 1;
  }
  // peel s = NK-2
  asm volatile("s_waitcnt vmcnt(4)" ::: "memory");
  __builtin_amdgcn_s_barrier();
  asm volatile("" ::: "memory");
  kstep(rd);
  rd = (rd == 2) ? 0 : rd + 1;
  // peel s = NK-1
  asm volatile("s_waitcnt vmcnt(0)" ::: "memory");
  __builtin_amdgcn_s_barrier();
  asm volatile("" ::: "memory");
  kstep(rd);

  #pragma unroll
  for (int i = 0; i < 4; i++) {
    const int row = bm0 + wr * 64 + i * 16 + kg * 4;
    #pragma unroll
    for (int j = 0; j < 4; j++) {
      const int col = bn0 + wc * 64 + j * 16 + lrow;
      const float sc = scale[col], bi = bias[col];
      #pragma unroll
      for (int r = 0; r < 4; r++) {
        float v = acc[i][j][r] * sc + bi;
        v = v > 0.f ? v : 0.f;
        out[(long)(row + r) * COUT + col] = f2bf(v);
      }
    }
  }
}

// ---------------------------------------------------------------------------
// conv2 + fused 1x1 conv3 + bias + softmax (R8 verbatim — passed, keeps h3
// traffic + separate kernel eliminated).  3-buffer, single barrier, vmcnt(4).
// ---------------------------------------------------------------------------
__global__ __launch_bounds__(256)
void conv2_fused(const unsigned short* __restrict__ inP,
                 const unsigned short* __restrict__ wT,
                 const float* __restrict__ scale, const float* __restrict__ bias,
                 const unsigned short* __restrict__ w3b, const float* __restrict__ b3,
                 float* __restrict__ out) {
  constexpr int CIN = 256, NK = 72;
  constexpr int Wout = 192, Hp = 194, Wp = 194;
  constexpr int HWo = 192 * 192;
  constexpr int KT = 9 * CIN;
  __shared__ unsigned short pool[6 * 4096];   // 48KB: 3xA @0, 3xB @12288; h-tile reuses @0
  const int tid = threadIdx.x;
  const int chunk = gridDim.x >> 3;
  const int bid = (blockIdx.x & 7) * chunk + (blockIdx.x >> 3);
  const int bm0 = bid * 128;                  // nbN = 1, bn0 = 0

  const int rA = tid >> 2;
  const int ch8 = (((tid & 3) ^ ((tid >> 3) & 3)) * 8);
  const int m0 = bm0 + rA, m1 = m0 + 64;
  const int n0 = m0 / HWo; const int q0 = m0 - n0 * HWo;
  const int y0 = q0 / Wout, x0 = q0 - y0 * Wout;
  const int n1 = m1 / HWo; const int q1 = m1 - n1 * HWo;
  const int y1 = q1 / Wout, x1 = q1 - y1 * Wout;
  const unsigned short* gA0 = inP + ((long)(n0 * Hp + y0) * Wp + x0) * CIN + ch8;
  const unsigned short* gA1 = inP + ((long)(n1 * Hp + y1) * Wp + x1) * CIN + ch8;
  const unsigned short* gB0 = wT + (long)rA * KT + ch8;
  const unsigned short* gB1 = wT + (long)(rA + 64) * KT + ch8;

  const int lane = tid & 63;
  const int wv = tid >> 6;
  const int wr = wv >> 1, wc = wv & 1;
  const int lrow = lane & 15, kg = lane >> 4;
  const int arow = wr * 64 + lrow;
  const int aoff = arow * 32 + (kg ^ ((arow >> 1) & 3)) * 8;
  const int brow = wc * 64 + lrow;
  const int boff = brow * 32 + (kg ^ ((brow >> 1) & 3)) * 8;

  f32x4 acc[4][4];
  const f32x4 zero = {0.f, 0.f, 0.f, 0.f};
  #pragma unroll
  for (int i = 0; i < 4; i++)
    #pragma unroll
    for (int j = 0; j < 4; j++) acc[i][j] = zero;

  auto stage = [&](int b, int s) {
    const int cblk = s / 9;
    const int t = s - cblk * 9;
    const int ty = t / 3, tx = t - ty * 3;
    const long offA = (long)(ty * Wp + tx) * CIN + cblk * 32;
    gload16(&pool[b * 4096 + tid * 8], gA0 + offA);
    gload16(&pool[b * 4096 + 2048 + tid * 8], gA1 + offA);
    const long k0 = (long)s * 32;
    gload16(&pool[12288 + b * 4096 + tid * 8], gB0 + k0);
    gload16(&pool[12288 + b * 4096 + 2048 + tid * 8], gB1 + k0);
  };

  auto kstep = [&](int rd) {
    const unsigned short* A = &pool[rd * 4096];
    const unsigned short* B = &pool[12288 + rd * 4096];
    short8 af[4], bfr[4];
    #pragma unroll
    for (int i = 0; i < 4; i++) af[i] = *(const short8*)&A[aoff + i * 512];
    #pragma unroll
    for (int j = 0; j < 4; j++) bfr[j] = *(const short8*)&B[boff + j * 512];
    __builtin_amdgcn_s_setprio(1);
    #pragma unroll
    for (int i = 0; i < 4; i++)
      #pragma unroll
      for (int j = 0; j < 4; j++)
        acc[i][j] = __builtin_amdgcn_mfma_f32_16x16x32_bf16(af[i], bfr[j], acc[i][j], 0, 0, 0);
    __builtin_amdgcn_s_setprio(0);
  };

  stage(0, 0);
  stage(1, 1);
  int rd = 0;
  for (int s = 0; s < NK; ++s) {
    if (s < NK - 1)
      asm volatile("s_waitcnt vmcnt(4)" ::: "memory");   // stage(s) landed; s+1 in flight
    else
      asm volatile("s_waitcnt vmcnt(0)" ::: "memory");
    __builtin_amdgcn_s_barrier();
    asm volatile("" ::: "memory");
    kstep(rd);
    if (s + 2 < NK) stage((rd + 2 >= 3) ? rd - 1 : rd + 2, s + 2);
    rd = (rd == 2) ? 0 : rd + 1;
  }

  // ---- fused epilogue: BN+ReLU -> LDS h-tile [128px][128ch], slot-swizzled
  asm volatile("s_waitcnt lgkmcnt(0)" ::: "memory");
  __builtin_amdgcn_s_barrier();
  asm volatile("" ::: "memory");
  #pragma unroll
  for (int j = 0; j < 4; j++) {
    const int ch = wc * 64 + j * 16 + lrow;
    const float sc = scale[ch], bi = bias[ch];
    #pragma unroll
    for (int i = 0; i < 4; i++) {
      const int pxb = wr * 64 + i * 16 + kg * 4;
      #pragma unroll
      for (int r = 0; r < 4; r++) {
        const int px = pxb + r;
        float v = acc[i][j][r] * sc + bi;
        v = v > 0.f ? v : 0.f;
        pool[px * 128 + (ch ^ ((px & 7) << 3))] = f2bf(v);
      }
    }
  }
  asm volatile("s_waitcnt lgkmcnt(0)" ::: "memory");
  __builtin_amdgcn_s_barrier();
  asm volatile("" ::: "memory");

  // ---- conv3 (21x128) + softmax, 32 px per wave (verified k_conv3_mfma map)
  #pragma unroll
  for (int g = 0; g < 2; g++) {
    const int px = wv * 32 + g * 16 + lrow;
    f32x4 acc0 = {0.f, 0.f, 0.f, 0.f}, acc1 = {0.f, 0.f, 0.f, 0.f};
    #pragma unroll
    for (int s = 0; s < 4; s++) {
      const int ch0 = s * 32 + kg * 8;
      const short8 b = *(const short8*)&pool[px * 128 + (ch0 ^ ((px & 7) << 3))];
      const short8 a0 = *(const short8*)&w3b[lrow * 128 + ch0];
      const short8 a1 = *(const short8*)&w3b[(16 + lrow) * 128 + ch0];
      acc0 = __builtin_amdgcn_mfma_f32_16x16x32_bf16(a0, b, acc0, 0, 0, 0);
      acc1 = __builtin_amdgcn_mfma_f32_16x16x32_bf16(a1, b, acc1, 0, 0, 0);
    }
    float lg[8], mx = -1e30f;
    #pragma unroll
    for (int r = 0; r < 4; r++) {
      lg[r] = acc0[r] + b3[kg * 4 + r];
      mx = fmaxf(mx, lg[r]);
    }
    #pragma unroll
    for (int r = 0; r < 4; r++) {
      const int c = 16 + kg * 4 + r;
      if (c < 21) { lg[4 + r] = acc1[r] + b3[c]; mx = fmaxf(mx, lg[4 + r]); }
      else lg[4 + r] = -1e30f;
    }
    mx = fmaxf(mx, __shfl_xor(mx, 16)); mx = fmaxf(mx, __shfl_xor(mx, 32));
    float sum = 0.f;
    #pragma unroll
    for (int k = 0; k < 8; k++) {
      lg[k] = (lg[k] > -1e29f) ? __expf(lg[k] - mx) : 0.f;
      sum += lg[k];
    }
    sum += __shfl_xor(sum, 16); sum += __shfl_xor(sum, 32);
    const float inv = 1.f / sum;
    const int m = bm0 + px;
    const int n = m / HWo;
    const int q = m - n * HWo;
    #pragma unroll
    for (int r = 0; r < 4; r++)
      out[((long)n * 21 + kg * 4 + r) * (long)HWo + q] = lg[r] * inv;
    #pragma unroll
    for (int r = 0; r < 4; r++) {
      const int c = 16 + kg * 4 + r;
      if (c < 21) out[((long)n * 21 + c) * (long)HWo + q] = lg[4 + r] * inv;
    }
  }
}

// ---------------------------------------------------------------------------
// jax bilinear x2 -> padded h2P[8][194][194][256]
// ---------------------------------------------------------------------------
__global__ void k_upsample(const unsigned short* __restrict__ h1,
                           unsigned short* __restrict__ h2P) {
  const int idx = blockIdx.x * 256 + threadIdx.x;  // 8*192*192*32
  const int c8 = (idx & 31) * 8;
  const int p = idx >> 5;
  const int n = p / 36864; const int rr = p - n * 36864;
  const int Y = rr / 192, X = rr - Y * 192;
  const int ky = Y >> 1, kx = X >> 1;
  int yA, yB, xA, xB; float wyA, wyB, wxA, wxB;
  if ((Y & 1) == 0) { yA = ky > 0 ? ky - 1 : 0; yB = ky; wyA = 0.25f; wyB = 0.75f; }
  else { yA = ky; yB = ky < 95 ? ky + 1 : 95; wyA = 0.75f; wyB = 0.25f; }
  if ((X & 1) == 0) { xA = kx > 0 ? kx - 1 : 0; xB = kx; wxA = 0.25f; wxB = 0.75f; }
  else { xA = kx; xB = kx < 95 ? kx + 1 : 95; wxA = 0.75f; wxB = 0.25f; }
  const unsigned short* hb = h1 + (long)n * 96 * 96 * 256 + c8;
  const short8 vaa = *(const short8*)&hb[((long)yA * 96 + xA) * 256];
  const short8 vab = *(const short8*)&hb[((long)yA * 96 + xB) * 256];
  const short8 vba = *(const short8*)&hb[((long)yB * 96 + xA) * 256];
  const short8 vbb = *(const short8*)&hb[((long)yB * 96 + xB) * 256];
  short8 o;
  #pragma unroll
  for (int j = 0; j < 8; j++) {
    float v = wyA * (wxA * bf2f((unsigned short)vaa[j]) + wxB * bf2f((unsigned short)vab[j])) +
              wyB * (wxA * bf2f((unsigned short)vba[j]) + wxB * bf2f((unsigned short)vbb[j]));
    o[j] = (short)f2bf(v);
  }
  *(short8*)&h2P[(((long)n * 194 + Y + 1) * 194 + X + 1) * 256 + c8] = o;
}

// ---------------------------------------------------------------------------
extern "C" void kernel_launch(void* const* d_in, const int* in_sizes, int n_in,
                              void* d_out, int out_size, void* d_ws, size_t ws_size,
                              hipStream_t stream) {
  const float* feature = (const float*)d_in[0];
  const float* gp = (const float*)d_in[1];
  const float* w1 = (const float*)d_in[2];
  const float* g1 = (const float*)d_in[3];
  const float* b1 = (const float*)d_in[4];
  const float* m1 = (const float*)d_in[5];
  const float* v1 = (const float*)d_in[6];
  const float* w2 = (const float*)d_in[7];
  const float* g2 = (const float*)d_in[8];
  const float* b2 = (const float*)d_in[9];
  const float* m2 = (const float*)d_in[10];
  const float* v2 = (const float*)d_in[11];
  const float* w3 = (const float*)d_in[12];
  const float* b3 = (const float*)d_in[13];
  float* out = (float*)d_out;

  char* ws = (char*)d_ws;
  size_t off = 0;
  auto alloc = [&](size_t bytes) -> void* {
    void* p = ws + off;
    off += (bytes + 255) & ~(size_t)255;
    return p;
  };
  signed char* lab = (signed char*)alloc(73728);
  signed char* em = (signed char*)alloc(73728);
  float* objs = (float*)alloc(8 * 21 * 512 * 4);
  float* o2 = (float*)alloc(168 * 4);
  unsigned short* objs_c = (unsigned short*)alloc((size_t)8 * 32 * 512 * 2);
  float* dist = (float*)alloc((size_t)8 * 21 * 9216 * 4);
  unsigned short* w1t = (unsigned short*)alloc((size_t)256 * 4608 * 2);
  unsigned short* w2t = (unsigned short*)alloc((size_t)128 * 2304 * 2);
  unsigned short* w3b = (unsigned short*)alloc((size_t)32 * 128 * 2);
  float* s1 = (float*)alloc(256 * 4);
  float* bb1 = (float*)alloc(256 * 4);
  float* s2 = (float*)alloc(128 * 4);
  float* bb2 = (float*)alloc(128 * 4);
  const size_t fuP_bytes = (size_t)8 * 98 * 98 * 512 * 2;    // 78.7 MB
  unsigned short* fuP = (unsigned short*)alloc(fuP_bytes);
  const size_t h1_bytes = (size_t)8 * 96 * 96 * 256 * 2;     // 37.7 MB
  unsigned short* h1 = (unsigned short*)alloc(h1_bytes);
  const size_t h2P_bytes = (size_t)8 * 194 * 194 * 256 * 2;  // 154.1 MB
  unsigned short* h2P = (unsigned short*)alloc(h2P_bytes);
  unsigned short* featT = h2P;   // featT (75.5 MB) dead before border(h2P)/upsample

  if (off > ws_size) return;  // workspace too small — fail loudly via wrong output

  k_prepbn<<<1, 256, 0, stream>>>(g1, b1, m1, v1, g2, b2, m2, v2, s1, bb1, s2, bb2);
  k_prepw1<<<4608, 256, 0, stream>>>(w1, w1t);
  k_prepw2<<<1152, 256, 0, stream>>>(w2, w2t);
  k_prepw3<<<16, 256, 0, stream>>>(w3, w3b);

  k_border<98, 98, 512><<<777, 256, 0, stream>>>(fuP);
  hipMemsetAsync(objs, 0, 8 * 21 * 512 * 4, stream);

  k_labels<<<288, 256, 0, stream>>>(gp, lab);
  k_em<<<288, 256, 0, stream>>>(lab, em);
  k_featT<<<dim3(288, 4), 256, 0, stream>>>(feature, featT);
  k_objsT<<<288, 256, 0, stream>>>(featT, em, objs);
  k_objfin<<<256, 64, 0, stream>>>(objs, o2, objs_c);
  k_dist_mfma<<<dim3(144, 8), 256, 0, stream>>>(featT, objs_c, o2, dist);
  k_fusion<<<1152, 256, 0, stream>>>(featT, em, dist, objs, fuP);

  conv3x3_gemm<512, 144><<<1152, 256, 0, stream>>>(fuP, w1t, s1, bb1, h1,
                                                   96, 96, 98, 98, 256, 2);
  // featT (aliasing h2P) is dead from here on
  k_border<194, 194, 256><<<772, 256, 0, stream>>>(h2P);
  k_upsample<<<36864, 256, 0, stream>>>(h1, h2P);
  conv2_fused<<<2304, 256, 0, stream>>>(h2P, w2t, s2, bb2, w3b, b3, out);
}

// Round 10
// 721.408 us; speedup vs baseline: 1.1096x; 1.0609x over previous
//
#include <hip/hip_runtime.h>
#include <cstdint>
#include <cstddef>

typedef __attribute__((ext_vector_type(4))) float f32x4;
typedef __attribute__((ext_vector_type(8))) short short8;

__device__ __forceinline__ float bf2f(unsigned short u) {
  union { unsigned int i; float f; } x; x.i = ((unsigned int)u) << 16; return x.f;
}
__device__ __forceinline__ unsigned short f2bf(float f) {
  union { float f; unsigned int i; } x; x.f = f;
  unsigned int r = x.i + 0x7fffu + ((x.i >> 16) & 1u);
  return (unsigned short)(r >> 16);
}
__device__ __forceinline__ void gload16(unsigned short* lds, const unsigned short* g) {
  __builtin_amdgcn_global_load_lds(
      (const __attribute__((address_space(1))) unsigned int*)g,
      (__attribute__((address_space(3))) unsigned int*)lds, 16, 0, 0);
}

// ---------------------------------------------------------------------------
// k_prep: all weight transforms + BN fold in one launch (block-range branch)
//   [0,4608)    w1t[256][4608]   K' = cblk*288 + tap*32 + ci_lo
//   [4608,5760) w2t[128][2304]
//   [5760,5776) w3b[32][128] (rows >=21 zero)
//   5776        BN fold
// ---------------------------------------------------------------------------
__global__ void k_prep(const float* __restrict__ w1, const float* __restrict__ w2,
                       const float* __restrict__ w3,
                       const float* __restrict__ g1, const float* __restrict__ b1,
                       const float* __restrict__ m1, const float* __restrict__ v1,
                       const float* __restrict__ g2, const float* __restrict__ b2,
                       const float* __restrict__ m2, const float* __restrict__ v2,
                       unsigned short* __restrict__ w1t, unsigned short* __restrict__ w2t,
                       unsigned short* __restrict__ w3b,
                       float* __restrict__ s1, float* __restrict__ bb1,
                       float* __restrict__ s2, float* __restrict__ bb2) {
  const int blk = blockIdx.x;
  const int tid = threadIdx.x;
  if (blk < 4608) {
    int i = blk * 256 + tid;
    int o = i / 4608, k = i - o * 4608;
    int cblk = k / 288, r = k - cblk * 288;
    int t = r >> 5, cl = r & 31;
    int ci = cblk * 32 + cl;
    int ty = t / 3, tx = t - ty * 3;
    w1t[i] = f2bf(w1[((o * 512 + ci) * 3 + ty) * 3 + tx]);
  } else if (blk < 5760) {
    int i = (blk - 4608) * 256 + tid;
    int o = i / 2304, k = i - o * 2304;
    int cblk = k / 288, r = k - cblk * 288;
    int t = r >> 5, cl = r & 31;
    int ci = cblk * 32 + cl;
    int ty = t / 3, tx = t - ty * 3;
    w2t[i] = f2bf(w2[((o * 256 + ci) * 3 + ty) * 3 + tx]);
  } else if (blk < 5776) {
    int i = (blk - 5760) * 256 + tid;
    int c = i >> 7, k = i & 127;
    w3b[i] = (c < 21) ? f2bf(w3[c * 128 + k]) : (unsigned short)0;
  } else {
    if (tid < 256) { float s = g1[tid] * rsqrtf(v1[tid] + 1e-5f); s1[tid] = s; bb1[tid] = b1[tid] - m1[tid] * s; }
    if (tid < 128) { float s = g2[tid] * rsqrtf(v2[tid] + 1e-5f); s2[tid] = s; bb2[tid] = b2[tid] - m2[tid] * s; }
  }
}

// ---------------------------------------------------------------------------
// k_labels_init: labels argmax [0,288) + fuP halo zero [288,1064) +
// objs zero [1064,1400)
// ---------------------------------------------------------------------------
__global__ void k_labels_init(const float* __restrict__ gp, signed char* __restrict__ lab,
                              unsigned short* __restrict__ fuP, float* __restrict__ objs) {
  const int blk = blockIdx.x;
  const int tid = threadIdx.x;
  if (blk < 288) {
    int p = blk * 256 + tid;
    int n = p / 9216, q = p - n * 9216;
    const float* g = gp + (long)n * 21 * 9216 + q;
    float best = g[0]; int bi = 0;
    #pragma unroll
    for (int c = 1; c < 21; c++) {
      float v = g[(long)c * 9216];
      if (v > best) { best = v; bi = c; }
    }
    lab[p] = (signed char)bi;
  } else if (blk < 1064) {
    // fuP halo: HP=WP=98, C=512
    int i = (blk - 288) * 256 + tid;       // < 198656 exact
    const int B = 2 * 98 + 2 * 96;         // 388
    const int cg = i & 63; int b = i >> 6;
    const int n = b / B; b -= n * B;
    int y, x;
    if (b < 98) { y = 0; x = b; }
    else if (b < 196) { y = 97; x = b - 98; }
    else { int r = b - 196; y = 1 + (r >> 1); x = (r & 1) ? 97 : 0; }
    short8 z = {0, 0, 0, 0, 0, 0, 0, 0};
    *(short8*)&fuP[(((long)n * 98 + y) * 98 + x) * 512 + cg * 8] = z;
  } else {
    int i = (blk - 1064) * 256 + tid;      // < 86016 exact
    objs[i] = 0.f;
  }
}

// em[p] = label if valid 5x5 window uniform, else -1
__global__ void k_em(const signed char* __restrict__ lab, signed char* __restrict__ em) {
  int p = blockIdx.x * 256 + threadIdx.x;
  int n = p / 9216, q = p - n * 9216, y = q / 96, x = q - y * 96;
  const signed char* L = lab + n * 9216;
  signed char l0 = L[q];
  bool uni = true;
  for (int dy = -2; dy <= 2; dy++) {
    int yy = y + dy; if (yy < 0 || yy > 95) continue;
    for (int dx = -2; dx <= 2; dx++) {
      int xx = x + dx; if (xx < 0 || xx > 95) continue;
      uni = uni && (L[yy * 96 + xx] == l0);
    }
  }
  em[p] = uni ? l0 : (signed char)-1;
}

// ---------------------------------------------------------------------------
// featT cast + objs accumulation fused: thread owns px, 128 f per block.y;
// per-class partials in LDS (atomic, rare path), flush present classes only.
// ---------------------------------------------------------------------------
__global__ __launch_bounds__(256)
void k_featT_objs(const float* __restrict__ feat, const signed char* __restrict__ em,
                  unsigned short* __restrict__ featT, float* __restrict__ objs) {
  __shared__ float part[21 * 128];
  __shared__ int pres[21];
  const int g = blockIdx.x * 256 + threadIdx.x;  // px index (blocks align within n)
  const int n = g / 9216, p = g - n * 9216;
  const int fg0 = blockIdx.y * 16;               // f in [blockIdx.y*128, +128)
  const int tid = threadIdx.x;
  for (int i = tid; i < 21 * 128; i += 256) part[i] = 0.f;
  if (tid < 21) pres[tid] = 0;
  __syncthreads();
  const int c0 = em[g];
  if (c0 >= 0) pres[c0] = 1;                     // benign same-value race
  const float* src = feat + (long)n * 512 * 9216 + p;
  unsigned short* dst = featT + ((long)n * 9216 + p) * 512;
  for (int fg = fg0; fg < fg0 + 16; fg++) {
    short8 o;
    float fv[8];
    #pragma unroll
    for (int j = 0; j < 8; j++) {
      fv[j] = src[(long)(fg * 8 + j) * 9216];
      o[j] = (short)f2bf(fv[j]);
    }
    *(short8*)&dst[fg * 8] = o;
    if (c0 >= 0) {
      const int lf0 = (fg - fg0) * 8;
      #pragma unroll
      for (int j = 0; j < 8; j++) atomicAdd(&part[c0 * 128 + lf0 + j], fv[j]);
    }
  }
  __syncthreads();
  for (int i = tid; i < 21 * 128; i += 256) {
    const int c = i >> 7, lf = i & 127;
    if (pres[c])
      atomicAdd(&objs[((long)n * 21 + c) * 512 + blockIdx.y * 128 + lf],
                part[i] * (1.0f / 9216.0f));
  }
}

// o2 + objs_c (bf16, rows >=21 zero) in one pass.  grid 256 = 8n x 32c, 64 thr
__global__ void k_objfin(const float* __restrict__ objs, float* __restrict__ o2,
                         unsigned short* __restrict__ oc) {
  const int b = blockIdx.x;
  const int n = b >> 5, c = b & 31;
  const int lane = threadIdx.x;
  unsigned short* dst = oc + ((long)n * 32 + c) * 512;
  if (c < 21) {
    const float* o = objs + ((long)n * 21 + c) * 512;
    float s = 0.f;
    for (int f = lane; f < 512; f += 64) {
      float v = o[f];
      s += v * v;
      dst[f] = f2bf(v);
    }
    #pragma unroll
    for (int off = 32; off; off >>= 1) s += __shfl_down(s, off);
    if (lane == 0) o2[n * 21 + c] = s;
  } else {
    for (int f = lane; f < 512; f += 64) dst[f] = 0;
  }
}

// ---------------------------------------------------------------------------
// dist (MFMA, verified R4 body) + fusion fused: same 64-px/block partition.
// Phase 1 writes softmax'd dist to LDS dl[64][21]; phase 2 = fusion body.
// ---------------------------------------------------------------------------
__global__ __launch_bounds__(256)
void k_dist_fusion(const unsigned short* __restrict__ featT,
                   const unsigned short* __restrict__ objs_c,
                   const float* __restrict__ o2, const float* __restrict__ objs,
                   const signed char* __restrict__ em,
                   unsigned short* __restrict__ fuP) {
  __shared__ float ob[21 * 512];
  __shared__ float dl[64][21];
  __shared__ signed char eml[64];
  const int n = blockIdx.y;
  const int p0 = blockIdx.x * 64;    // grid.x = 144
  const int tid = threadIdx.x;
  const int w = tid >> 6, lane = tid & 63;
  const int lrow = lane & 15, kg = lane >> 4;

  // cooperative loads for phase 2 (overlap with phase-1 compute)
  for (int i = tid; i < 21 * 512; i += 256) ob[i] = objs[(long)n * 21 * 512 + i];
  if (tid < 64) eml[tid] = em[n * 9216 + p0 + tid];

  // ---- phase 1: dist for px = p0 + w*16 + lrow
  const int px = p0 + w * 16 + lrow;
  const unsigned short* fb = featT + ((long)n * 9216 + px) * 512 + kg * 8;
  const unsigned short* a0p = objs_c + ((long)n * 32 + lrow) * 512 + kg * 8;
  const unsigned short* a1p = a0p + 16 * 512;
  f32x4 acc0 = {0.f, 0.f, 0.f, 0.f}, acc1 = {0.f, 0.f, 0.f, 0.f};
  float x2 = 0.f;
  #pragma unroll
  for (int s = 0; s < 16; s++) {
    const short8 b = *(const short8*)&fb[s * 32];
    const short8 a0 = *(const short8*)&a0p[s * 32];
    const short8 a1 = *(const short8*)&a1p[s * 32];
    acc0 = __builtin_amdgcn_mfma_f32_16x16x32_bf16(a0, b, acc0, 0, 0, 0);
    acc1 = __builtin_amdgcn_mfma_f32_16x16x32_bf16(a1, b, acc1, 0, 0, 0);
    #pragma unroll
    for (int j = 0; j < 8; j++) { float v = bf2f((unsigned short)b[j]); x2 += v * v; }
  }
  x2 += __shfl_xor(x2, 16); x2 += __shfl_xor(x2, 32);
  float cd[8], mx = -1e30f;
  #pragma unroll
  for (int r = 0; r < 4; r++) {
    const int c = kg * 4 + r;
    float d2 = x2 + o2[n * 21 + c] - 2.f * acc0[r];
    cd[r] = sqrtf(fmaxf(d2, 0.f)); mx = fmaxf(mx, cd[r]);
  }
  #pragma unroll
  for (int r = 0; r < 4; r++) {
    const int c = 16 + kg * 4 + r;
    if (c < 21) {
      float d2 = x2 + o2[n * 21 + c] - 2.f * acc1[r];
      cd[4 + r] = sqrtf(fmaxf(d2, 0.f)); mx = fmaxf(mx, cd[4 + r]);
    } else cd[4 + r] = -1e30f;
  }
  mx = fmaxf(mx, __shfl_xor(mx, 16)); mx = fmaxf(mx, __shfl_xor(mx, 32));
  float sum = 0.f;
  #pragma unroll
  for (int k = 0; k < 8; k++) {
    cd[k] = (cd[k] > -1e29f) ? __expf(cd[k] - mx) : 0.f;
    sum += cd[k];
  }
  sum += __shfl_xor(sum, 16); sum += __shfl_xor(sum, 32);
  const float inv = 1.f / sum;
  const int lpx = w * 16 + lrow;
  #pragma unroll
  for (int r = 0; r < 4; r++) dl[lpx][kg * 4 + r] = 1.f - cd[r] * inv;
  #pragma unroll
  for (int r = 0; r < 4; r++) {
    const int c = 16 + kg * 4 + r;
    if (c < 21) dl[lpx][c] = 1.f - cd[4 + r] * inv;
  }
  __syncthreads();

  // ---- phase 2: fusion (verified R4 body; dl from LDS)
  const int px2 = tid & 63;
  const int fg = (tid >> 6) * 8;
  const int q = p0 + px2;
  const int y = q / 96, x = q - y * 96;
  unsigned short* dst = fuP + (((long)n * 98 + y + 1) * 98 + (x + 1)) * 512;
  const bool t = eml[px2] < 0;
  const unsigned short* srcT = featT + ((long)n * 9216 + q) * 512;
  for (int f0 = 0; f0 < 512; f0 += 32) {
    short8 o;
    const short8 fvv = *(const short8*)&srcT[f0 + fg];
    #pragma unroll
    for (int j = 0; j < 8; j++) {
      const int f = f0 + fg + j;
      float fv = bf2f((unsigned short)fvv[j]);
      if (t) {
        float of = 0.f;
        #pragma unroll
        for (int c = 0; c < 21; c++) of += dl[px2][c] * ob[c * 512 + f];
        fv = 0.1f * fv + 0.9f * of;
      }
      o[j] = (short)f2bf(fv);
    }
    *(short8*)&dst[fg] = o;
    dst += 32;
  }
}

// ---------------------------------------------------------------------------
// conv1: implicit-GEMM 3x3, 128x128 tile, BK=32, 4 waves (R5 verbatim —
// measured best 253-257us).  3-buffer rotation, prefetch depth 2, dual
// s_barrier + counted vmcnt(8), tail peeled 4/0.
// ---------------------------------------------------------------------------
template <int CIN, int NK>
__global__ __launch_bounds__(256)
void conv3x3_gemm(const unsigned short* __restrict__ inP,
                  const unsigned short* __restrict__ wT,
                  const float* __restrict__ scale, const float* __restrict__ bias,
                  unsigned short* __restrict__ out,
                  int Hout, int Wout, int Hp, int Wp, int COUT, int nbN) {
  __shared__ unsigned short ldsA[3][4096];
  __shared__ unsigned short ldsB[3][4096];
  const int tid = threadIdx.x;
  const int chunk = gridDim.x >> 3;
  const int bid = (blockIdx.x & 7) * chunk + (blockIdx.x >> 3);
  const int mb = bid / nbN, nb = bid - mb * nbN;
  const int bm0 = mb * 128, bn0 = nb * 128;
  const int KT = 9 * CIN;
  const int HWo = Hout * Wout;

  const int rA = tid >> 2;
  const int ch8 = (((tid & 3) ^ ((tid >> 3) & 3)) * 8);
  const int m0 = bm0 + rA, m1 = m0 + 64;
  const int n0 = m0 / HWo; const int q0 = m0 - n0 * HWo;
  const int y0 = q0 / Wout, x0 = q0 - y0 * Wout;
  const int n1 = m1 / HWo; const int q1 = m1 - n1 * HWo;
  const int y1 = q1 / Wout, x1 = q1 - y1 * Wout;
  const unsigned short* gA0 = inP + ((long)(n0 * Hp + y0) * Wp + x0) * CIN + ch8;
  const unsigned short* gA1 = inP + ((long)(n1 * Hp + y1) * Wp + x1) * CIN + ch8;
  const unsigned short* gB0 = wT + (long)(bn0 + rA) * KT + ch8;
  const unsigned short* gB1 = wT + (long)(bn0 + rA + 64) * KT + ch8;

  const int lane = tid & 63;
  const int wv = tid >> 6;
  const int wr = wv >> 1, wc = wv & 1;
  const int lrow = lane & 15, kg = lane >> 4;
  const int arow = wr * 64 + lrow;
  const int aoff = arow * 32 + (kg ^ ((arow >> 1) & 3)) * 8;
  const int brow = wc * 64 + lrow;
  const int boff = brow * 32 + (kg ^ ((brow >> 1) & 3)) * 8;

  f32x4 acc[4][4];
  const f32x4 zero = {0.f, 0.f, 0.f, 0.f};
  #pragma unroll
  for (int i = 0; i < 4; i++)
    #pragma unroll
    for (int j = 0; j < 4; j++) acc[i][j] = zero;

  auto stage = [&](int b, int s) {
    const int cblk = s / 9;            // s = cblk*9 + t  (tap-fastest)
    const int t = s - cblk * 9;
    const int ty = t / 3, tx = t - ty * 3;
    const long offA = (long)(ty * Wp + tx) * CIN + cblk * 32;
    gload16(&ldsA[b][tid * 8], gA0 + offA);
    gload16(&ldsA[b][2048 + tid * 8], gA1 + offA);
    const long k0 = (long)s * 32;
    gload16(&ldsB[b][tid * 8], gB0 + k0);
    gload16(&ldsB[b][2048 + tid * 8], gB1 + k0);
  };

  auto kstep = [&](int rd) {
    const unsigned short* A = ldsA[rd];
    const unsigned short* B = ldsB[rd];
    short8 af[4], bfr[4];
    #pragma unroll
    for (int i = 0; i < 4; i++) af[i] = *(const short8*)&A[aoff + i * 512];
    #pragma unroll
    for (int j = 0; j < 4; j++) bfr[j] = *(const short8*)&B[boff + j * 512];
    __builtin_amdgcn_s_setprio(1);
    #pragma unroll
    for (int i = 0; i < 4; i++)
      #pragma unroll
      for (int j = 0; j < 4; j++)
        acc[i][j] = __builtin_amdgcn_mfma_f32_16x16x32_bf16(af[i], bfr[j], acc[i][j], 0, 0, 0);
    __builtin_amdgcn_s_setprio(0);
  };

  // prologue: 2 stages in flight
  stage(0, 0);
  stage(1, 1);
  int rd = 0, prev = 2;
  for (int s = 0; s < NK - 2; ++s) {
    __builtin_amdgcn_s_barrier();                    // barrier_A: buf[prev] free
    asm volatile("" ::: "memory");
    stage(prev, s + 2);
    asm volatile("s_waitcnt vmcnt(8)" ::: "memory"); // my buf[rd] loads landed
    __builtin_amdgcn_s_barrier();                    // barrier_B: all waves' landed
    asm volatile("" ::: "memory");
    kstep(rd);
    prev = rd; rd = (rd == 2) ? 0 : rd + 1;
  }
  // peel s = NK-2
  asm volatile("s_waitcnt vmcnt(4)" ::: "memory");
  __builtin_amdgcn_s_barrier();
  asm volatile("" ::: "memory");
  kstep(rd);
  rd = (rd == 2) ? 0 : rd + 1;
  // peel s = NK-1
  asm volatile("s_waitcnt vmcnt(0)" ::: "memory");
  __builtin_amdgcn_s_barrier();
  asm volatile("" ::: "memory");
  kstep(rd);

  #pragma unroll
  for (int i = 0; i < 4; i++) {
    const int row = bm0 + wr * 64 + i * 16 + kg * 4;
    #pragma unroll
    for (int j = 0; j < 4; j++) {
      const int col = bn0 + wc * 64 + j * 16 + lrow;
      const float sc = scale[col], bi = bias[col];
      #pragma unroll
      for (int r = 0; r < 4; r++) {
        float v = acc[i][j][r] * sc + bi;
        v = v > 0.f ? v : 0.f;
        out[(long)(row + r) * COUT + col] = f2bf(v);
      }
    }
  }
}

// ---------------------------------------------------------------------------
// conv2 + fused 1x1 conv3 + bias + softmax (R8 verbatim, passed twice)
// ---------------------------------------------------------------------------
__global__ __launch_bounds__(256)
void conv2_fused(const unsigned short* __restrict__ inP,
                 const unsigned short* __restrict__ wT,
                 const float* __restrict__ scale, const float* __restrict__ bias,
                 const unsigned short* __restrict__ w3b, const float* __restrict__ b3,
                 float* __restrict__ out) {
  constexpr int CIN = 256, NK = 72;
  constexpr int Wout = 192, Hp = 194, Wp = 194;
  constexpr int HWo = 192 * 192;
  constexpr int KT = 9 * CIN;
  __shared__ unsigned short pool[6 * 4096];   // 48KB: 3xA @0, 3xB @12288; h-tile reuses @0
  const int tid = threadIdx.x;
  const int chunk = gridDim.x >> 3;
  const int bid = (blockIdx.x & 7) * chunk + (blockIdx.x >> 3);
  const int bm0 = bid * 128;                  // nbN = 1, bn0 = 0

  const int rA = tid >> 2;
  const int ch8 = (((tid & 3) ^ ((tid >> 3) & 3)) * 8);
  const int m0 = bm0 + rA, m1 = m0 + 64;
  const int n0 = m0 / HWo; const int q0 = m0 - n0 * HWo;
  const int y0 = q0 / Wout, x0 = q0 - y0 * Wout;
  const int n1 = m1 / HWo; const int q1 = m1 - n1 * HWo;
  const int y1 = q1 / Wout, x1 = q1 - y1 * Wout;
  const unsigned short* gA0 = inP + ((long)(n0 * Hp + y0) * Wp + x0) * CIN + ch8;
  const unsigned short* gA1 = inP + ((long)(n1 * Hp + y1) * Wp + x1) * CIN + ch8;
  const unsigned short* gB0 = wT + (long)rA * KT + ch8;
  const unsigned short* gB1 = wT + (long)(rA + 64) * KT + ch8;

  const int lane = tid & 63;
  const int wv = tid >> 6;
  const int wr = wv >> 1, wc = wv & 1;
  const int lrow = lane & 15, kg = lane >> 4;
  const int arow = wr * 64 + lrow;
  const int aoff = arow * 32 + (kg ^ ((arow >> 1) & 3)) * 8;
  const int brow = wc * 64 + lrow;
  const int boff = brow * 32 + (kg ^ ((brow >> 1) & 3)) * 8;

  f32x4 acc[4][4];
  const f32x4 zero = {0.f, 0.f, 0.f, 0.f};
  #pragma unroll
  for (int i = 0; i < 4; i++)
    #pragma unroll
    for (int j = 0; j < 4; j++) acc[i][j] = zero;

  auto stage = [&](int b, int s) {
    const int cblk = s / 9;
    const int t = s - cblk * 9;
    const int ty = t / 3, tx = t - ty * 3;
    const long offA = (long)(ty * Wp + tx) * CIN + cblk * 32;
    gload16(&pool[b * 4096 + tid * 8], gA0 + offA);
    gload16(&pool[b * 4096 + 2048 + tid * 8], gA1 + offA);
    const long k0 = (long)s * 32;
    gload16(&pool[12288 + b * 4096 + tid * 8], gB0 + k0);
    gload16(&pool[12288 + b * 4096 + 2048 + tid * 8], gB1 + k0);
  };

  auto kstep = [&](int rd) {
    const unsigned short* A = &pool[rd * 4096];
    const unsigned short* B = &pool[12288 + rd * 4096];
    short8 af[4], bfr[4];
    #pragma unroll
    for (int i = 0; i < 4; i++) af[i] = *(const short8*)&A[aoff + i * 512];
    #pragma unroll
    for (int j = 0; j < 4; j++) bfr[j] = *(const short8*)&B[boff + j * 512];
    __builtin_amdgcn_s_setprio(1);
    #pragma unroll
    for (int i = 0; i < 4; i++)
      #pragma unroll
      for (int j = 0; j < 4; j++)
        acc[i][j] = __builtin_amdgcn_mfma_f32_16x16x32_bf16(af[i], bfr[j], acc[i][j], 0, 0, 0);
    __builtin_amdgcn_s_setprio(0);
  };

  stage(0, 0);
  stage(1, 1);
  int rd = 0;
  for (int s = 0; s < NK; ++s) {
    if (s < NK - 1)
      asm volatile("s_waitcnt vmcnt(4)" ::: "memory");   // stage(s) landed; s+1 in flight
    else
      asm volatile("s_waitcnt vmcnt(0)" ::: "memory");
    __builtin_amdgcn_s_barrier();
    asm volatile("" ::: "memory");
    kstep(rd);
    if (s + 2 < NK) stage((rd + 2 >= 3) ? rd - 1 : rd + 2, s + 2);
    rd = (rd == 2) ? 0 : rd + 1;
  }

  // ---- fused epilogue: BN+ReLU -> LDS h-tile [128px][128ch], slot-swizzled
  asm volatile("s_waitcnt lgkmcnt(0)" ::: "memory");
  __builtin_amdgcn_s_barrier();
  asm volatile("" ::: "memory");
  #pragma unroll
  for (int j = 0; j < 4; j++) {
    const int ch = wc * 64 + j * 16 + lrow;
    const float sc = scale[ch], bi = bias[ch];
    #pragma unroll
    for (int i = 0; i < 4; i++) {
      const int pxb = wr * 64 + i * 16 + kg * 4;
      #pragma unroll
      for (int r = 0; r < 4; r++) {
        const int px = pxb + r;
        float v = acc[i][j][r] * sc + bi;
        v = v > 0.f ? v : 0.f;
        pool[px * 128 + (ch ^ ((px & 7) << 3))] = f2bf(v);
      }
    }
  }
  asm volatile("s_waitcnt lgkmcnt(0)" ::: "memory");
  __builtin_amdgcn_s_barrier();
  asm volatile("" ::: "memory");

  // ---- conv3 (21x128) + softmax, 32 px per wave (verified k_conv3_mfma map)
  #pragma unroll
  for (int g = 0; g < 2; g++) {
    const int px = wv * 32 + g * 16 + lrow;
    f32x4 acc0 = {0.f, 0.f, 0.f, 0.f}, acc1 = {0.f, 0.f, 0.f, 0.f};
    #pragma unroll
    for (int s = 0; s < 4; s++) {
      const int ch0 = s * 32 + kg * 8;
      const short8 b = *(const short8*)&pool[px * 128 + (ch0 ^ ((px & 7) << 3))];
      const short8 a0 = *(const short8*)&w3b[lrow * 128 + ch0];
      const short8 a1 = *(const short8*)&w3b[(16 + lrow) * 128 + ch0];
      acc0 = __builtin_amdgcn_mfma_f32_16x16x32_bf16(a0, b, acc0, 0, 0, 0);
      acc1 = __builtin_amdgcn_mfma_f32_16x16x32_bf16(a1, b, acc1, 0, 0, 0);
    }
    float lg[8], mx = -1e30f;
    #pragma unroll
    for (int r = 0; r < 4; r++) {
      lg[r] = acc0[r] + b3[kg * 4 + r];
      mx = fmaxf(mx, lg[r]);
    }
    #pragma unroll
    for (int r = 0; r < 4; r++) {
      const int c = 16 + kg * 4 + r;
      if (c < 21) { lg[4 + r] = acc1[r] + b3[c]; mx = fmaxf(mx, lg[4 + r]); }
      else lg[4 + r] = -1e30f;
    }
    mx = fmaxf(mx, __shfl_xor(mx, 16)); mx = fmaxf(mx, __shfl_xor(mx, 32));
    float sum = 0.f;
    #pragma unroll
    for (int k = 0; k < 8; k++) {
      lg[k] = (lg[k] > -1e29f) ? __expf(lg[k] - mx) : 0.f;
      sum += lg[k];
    }
    sum += __shfl_xor(sum, 16); sum += __shfl_xor(sum, 32);
    const float inv = 1.f / sum;
    const int m = bm0 + px;
    const int n = m / HWo;
    const int q = m - n * HWo;
    #pragma unroll
    for (int r = 0; r < 4; r++)
      out[((long)n * 21 + kg * 4 + r) * (long)HWo + q] = lg[r] * inv;
    #pragma unroll
    for (int r = 0; r < 4; r++) {
      const int c = 16 + kg * 4 + r;
      if (c < 21) out[((long)n * 21 + c) * (long)HWo + q] = lg[4 + r] * inv;
    }
  }
}

// ---------------------------------------------------------------------------
// jax bilinear x2 -> padded h2P interior [0,36864) + h2P halo zero [36864,+772)
// ---------------------------------------------------------------------------
__global__ void k_upsample(const unsigned short* __restrict__ h1,
                           unsigned short* __restrict__ h2P) {
  if (blockIdx.x >= 36864) {
    // h2P halo: HP=WP=194, C=256
    int i = (blockIdx.x - 36864) * 256 + threadIdx.x;  // < 197632 exact
    const int B = 2 * 194 + 2 * 192;                   // 772
    const int cg = i & 31; int b = i >> 5;
    const int n = b / B; b -= n * B;
    int y, x;
    if (b < 194) { y = 0; x = b; }
    else if (b < 388) { y = 193; x = b - 194; }
    else { int r = b - 388; y = 1 + (r >> 1); x = (r & 1) ? 193 : 0; }
    short8 z = {0, 0, 0, 0, 0, 0, 0, 0};
    *(short8*)&h2P[(((long)n * 194 + y) * 194 + x) * 256 + cg * 8] = z;
    return;
  }
  const int idx = blockIdx.x * 256 + threadIdx.x;  // 8*192*192*32
  const int c8 = (idx & 31) * 8;
  const int p = idx >> 5;
  const int n = p / 36864; const int rr = p - n * 36864;
  const int Y = rr / 192, X = rr - Y * 192;
  const int ky = Y >> 1, kx = X >> 1;
  int yA, yB, xA, xB; float wyA, wyB, wxA, wxB;
  if ((Y & 1) == 0) { yA = ky > 0 ? ky - 1 : 0; yB = ky; wyA = 0.25f; wyB = 0.75f; }
  else { yA = ky; yB = ky < 95 ? ky + 1 : 95; wyA = 0.75f; wyB = 0.25f; }
  if ((X & 1) == 0) { xA = kx > 0 ? kx - 1 : 0; xB = kx; wxA = 0.25f; wxB = 0.75f; }
  else { xA = kx; xB = kx < 95 ? kx + 1 : 95; wxA = 0.75f; wxB = 0.25f; }
  const unsigned short* hb = h1 + (long)n * 96 * 96 * 256 + c8;
  const short8 vaa = *(const short8*)&hb[((long)yA * 96 + xA) * 256];
  const short8 vab = *(const short8*)&hb[((long)yA * 96 + xB) * 256];
  const short8 vba = *(const short8*)&hb[((long)yB * 96 + xA) * 256];
  const short8 vbb = *(const short8*)&hb[((long)yB * 96 + xB) * 256];
  short8 o;
  #pragma unroll
  for (int j = 0; j < 8; j++) {
    float v = wyA * (wxA * bf2f((unsigned short)vaa[j]) + wxB * bf2f((unsigned short)vab[j])) +
              wyB * (wxA * bf2f((unsigned short)vba[j]) + wxB * bf2f((unsigned short)vbb[j]));
    o[j] = (short)f2bf(v);
  }
  *(short8*)&h2P[(((long)n * 194 + Y + 1) * 194 + X + 1) * 256 + c8] = o;
}

// ---------------------------------------------------------------------------
extern "C" void kernel_launch(void* const* d_in, const int* in_sizes, int n_in,
                              void* d_out, int out_size, void* d_ws, size_t ws_size,
                              hipStream_t stream) {
  const float* feature = (const float*)d_in[0];
  const float* gp = (const float*)d_in[1];
  const float* w1 = (const float*)d_in[2];
  const float* g1 = (const float*)d_in[3];
  const float* b1 = (const float*)d_in[4];
  const float* m1 = (const float*)d_in[5];
  const float* v1 = (const float*)d_in[6];
  const float* w2 = (const float*)d_in[7];
  const float* g2 = (const float*)d_in[8];
  const float* b2 = (const float*)d_in[9];
  const float* m2 = (const float*)d_in[10];
  const float* v2 = (const float*)d_in[11];
  const float* w3 = (const float*)d_in[12];
  const float* b3 = (const float*)d_in[13];
  float* out = (float*)d_out;

  char* ws = (char*)d_ws;
  size_t off = 0;
  auto alloc = [&](size_t bytes) -> void* {
    void* p = ws + off;
    off += (bytes + 255) & ~(size_t)255;
    return p;
  };
  signed char* lab = (signed char*)alloc(73728);
  signed char* em = (signed char*)alloc(73728);
  float* objs = (float*)alloc(8 * 21 * 512 * 4);
  float* o2 = (float*)alloc(168 * 4);
  unsigned short* objs_c = (unsigned short*)alloc((size_t)8 * 32 * 512 * 2);
  unsigned short* w1t = (unsigned short*)alloc((size_t)256 * 4608 * 2);
  unsigned short* w2t = (unsigned short*)alloc((size_t)128 * 2304 * 2);
  unsigned short* w3b = (unsigned short*)alloc((size_t)32 * 128 * 2);
  float* s1 = (float*)alloc(256 * 4);
  float* bb1 = (float*)alloc(256 * 4);
  float* s2 = (float*)alloc(128 * 4);
  float* bb2 = (float*)alloc(128 * 4);
  const size_t fuP_bytes = (size_t)8 * 98 * 98 * 512 * 2;    // 78.7 MB
  unsigned short* fuP = (unsigned short*)alloc(fuP_bytes);
  const size_t h1_bytes = (size_t)8 * 96 * 96 * 256 * 2;     // 37.7 MB
  unsigned short* h1 = (unsigned short*)alloc(h1_bytes);
  const size_t h2P_bytes = (size_t)8 * 194 * 194 * 256 * 2;  // 154.1 MB
  unsigned short* h2P = (unsigned short*)alloc(h2P_bytes);
  unsigned short* featT = h2P;   // featT (75.5 MB) dead before border(h2P)/upsample

  if (off > ws_size) return;  // workspace too small — fail loudly via wrong output

  k_prep<<<5777, 256, 0, stream>>>(w1, w2, w3, g1, b1, m1, v1, g2, b2, m2, v2,
                                   w1t, w2t, w3b, s1, bb1, s2, bb2);
  k_labels_init<<<1400, 256, 0, stream>>>(gp, lab, fuP, objs);
  k_em<<<288, 256, 0, stream>>>(lab, em);
  k_featT_objs<<<dim3(288, 4), 256, 0, stream>>>(feature, em, featT, objs);
  k_objfin<<<256, 64, 0, stream>>>(objs, o2, objs_c);
  k_dist_fusion<<<dim3(144, 8), 256, 0, stream>>>(featT, objs_c, o2, objs, em, fuP);

  conv3x3_gemm<512, 144><<<1152, 256, 0, stream>>>(fuP, w1t, s1, bb1, h1,
                                                   96, 96, 98, 98, 256, 2);
  // featT (aliasing h2P) is dead from here on
  k_upsample<<<37636, 256, 0, stream>>>(h1, h2P);
  conv2_fused<<<2304, 256, 0, stream>>>(h2P, w2t, s2, bb2, w3b, b3, out);
}